// Round 1
// baseline (416.573 us; speedup 1.0000x reference)
//
#include <hip/hip_runtime.h>

// RPN forward on gfx950. Heavy op = 3x3 conv (2048->512) = 77.3 GFLOP -> bf16 MFMA.
// pos/neg assignment done in strict IEEE f32 (no contraction) to bit-match numpy ref.

typedef __bf16 bf16x8 __attribute__((ext_vector_type(8)));
typedef float floatx4 __attribute__((ext_vector_type(4)));

#define NB 4
#define NC 2048
#define NH 32
#define NW 32
#define NHID 512
#define NA 9
#define NG 20
#define NANC 9216            // NH*NW*NA
#define NM 4096              // NB*NH*NW

// workspace layout (bytes), all 256-aligned; total ~52.1 MB
#define OFF_XH    0ull            // [4][32][32][2048] bf16 = 16777216
#define OFF_WT    16777216ull     // [9][512][2048]    bf16 = 18874368
#define OFF_HIDF  35651584ull     // [4096][512]       f32  =  8388608
#define OFF_HIDB  44040192ull     // [4096][512]       bf16 =  4194304
#define OFF_WH    48234496ull     // [48][512]         bf16 =    49152
#define OFF_HB    48283648ull     // [48]              f32  (pad 256)
#define OFF_HEADS 48283904ull     // [4096][48]        f32  =   786432
#define OFF_IOU   49070336ull     // [4*9216][20]      f32  =  2949120
#define OFF_MAXG  52019456ull     // [4][20] uint bits (pad 512)
#define OFF_SUMS  52019968ull     // [2] f32

__device__ __forceinline__ unsigned short f2bf(float f) {
  unsigned int u = __float_as_uint(f);
  u = (u + 0x7fffu + ((u >> 16) & 1u)) >> 16;   // RNE
  return (unsigned short)u;
}

// anchor widths/heights: aw = repeat([2,4,6],3); ah = (scale*ratio) flattened
__constant__ float c_aw[9] = {2.f,2.f,2.f,4.f,4.f,4.f,6.f,6.f,6.f};
__constant__ float c_ah[9] = {1.f,2.f,3.f,2.f,4.f,6.f,3.f,6.f,9.f};

// ---------------- x: NCHW f32 -> NHWC bf16 ----------------
__global__ __launch_bounds__(256) void k_transpose_x(const float* __restrict__ x,
                                                     unsigned short* __restrict__ xh) {
  __shared__ float tile[32][33];
  const int c0 = blockIdx.x << 5;
  const int h  = blockIdx.y;
  const int b  = blockIdx.z;
  const int tx = threadIdx.x, ty = threadIdx.y;
  const float* src = x + (((size_t)b*NC + c0)*NH + h)*NW;
#pragma unroll
  for (int j = 0; j < 4; ++j) {
    const int c = ty + j*8;
    tile[c][tx] = src[(size_t)c*NH*NW + tx];
  }
  __syncthreads();
  unsigned short* dst = xh + (((size_t)b*NH + h)*NW)*NC + c0;
#pragma unroll
  for (int j = 0; j < 4; ++j) {
    const int w = ty + j*8;
    dst[(size_t)w*NC + tx] = f2bf(tile[tx][w]);
  }
}

// ---------------- w1: [O][C][3][3] f32 -> [g][O][C] bf16 ----------------
__global__ __launch_bounds__(256) void k_transpose_w(const float* __restrict__ w1,
                                                     unsigned short* __restrict__ wt) {
  const int t = blockIdx.x * 256 + threadIdx.x;   // t = o*2048 + c
  const int o = t >> 11, c = t & 2047;
  const float* src = w1 + (size_t)t * 9;          // 9 contiguous taps
#pragma unroll
  for (int g = 0; g < 9; ++g)
    wt[((size_t)g*NHID + o)*NC + c] = f2bf(src[g]);
}

// ---------------- head weights -> [48][512] bf16 + bias[48] ----------------
__global__ __launch_bounds__(256) void k_build_wh(const float* __restrict__ cw, const float* __restrict__ cb,
                                                  const float* __restrict__ rw, const float* __restrict__ rb,
                                                  unsigned short* __restrict__ wh, float* __restrict__ hb) {
  const int t = blockIdx.x*256 + threadIdx.x;     // 0..48*512-1
  const int n = t >> 9, c = t & 511;
  float v = 0.f;
  if (n < 9) v = cw[n*512 + c];
  else if (n < 45) v = rw[(n-9)*512 + c];
  wh[t] = f2bf(v);
  if (c == 0) {
    float bv = 0.f;
    if (n < 9) bv = cb[n];
    else if (n < 45) bv = rb[n-9];
    hb[n] = bv;
  }
}

// ---------------- conv 3x3 as implicit GEMM, bf16 MFMA ----------------
// M=4096 (b,h,w), N=512 (o), K=9*2048. Tile 128x128, BK=32, split-K=2 -> grid 32x4x2.
// 4 waves, each computes 64x64 via 4x4 of 16x16x32 MFMAs.
__global__ __launch_bounds__(256) void k_conv_gemm(const unsigned short* __restrict__ xh,
                                                   const unsigned short* __restrict__ wt,
                                                   float* __restrict__ hidf) {
  __shared__ unsigned short As[128*40] __attribute__((aligned(16)));   // [m][k] pad->40
  __shared__ unsigned short Bs[128*40] __attribute__((aligned(16)));   // [n][k]
  const int t = threadIdx.x;
  const int tileM = blockIdx.x, tileN = blockIdx.y, kz = blockIdx.z;
  const int b = tileM >> 3, h0 = (tileM & 7) << 2;
  const int o0 = tileN << 7;
  const int wv = t >> 6, lane = t & 63;
  const int wm = wv >> 1, wn = wv & 1;
  const int quad = lane >> 4, l16 = lane & 15;

  floatx4 acc[4][4];
#pragma unroll
  for (int mt = 0; mt < 4; ++mt)
#pragma unroll
    for (int nt = 0; nt < 4; ++nt)
      acc[mt][nt] = (floatx4){0.f, 0.f, 0.f, 0.f};

  const int arow0 = t >> 2, aseg = t & 3;   // 16B segment per thread, 2 rows apart by 64
  const unsigned short* xb = xh + (size_t)b*(32*32*2048) + kz*1024;

  for (int g = 0; g < 9; ++g) {
    const int dh = g/3 - 1, dw = g%3 - 1;
    const unsigned short* wg = wt + ((size_t)(g*512 + o0))*2048 + kz*1024;
    for (int c0 = 0; c0 < 1024; c0 += 32) {
#pragma unroll
      for (int i = 0; i < 2; ++i) {           // stage A (shifted, zero-padded)
        const int row = arow0 + (i << 6);
        const int hh = h0 + (row >> 5) + dh;
        const int ww = (row & 31) + dw;
        uint4 v = {0u, 0u, 0u, 0u};
        if ((unsigned)hh < 32u && (unsigned)ww < 32u)
          v = *(const uint4*)(xb + ((hh*32 + ww)*2048) + c0 + aseg*8);
        *(uint4*)(As + row*40 + aseg*8) = v;
      }
#pragma unroll
      for (int i = 0; i < 2; ++i) {           // stage B
        const int row = arow0 + (i << 6);
        uint4 v = *(const uint4*)(wg + (size_t)row*2048 + c0 + aseg*8);
        *(uint4*)(Bs + row*40 + aseg*8) = v;
      }
      __syncthreads();
      bf16x8 af[4], bw[4];
#pragma unroll
      for (int mt = 0; mt < 4; ++mt)
        af[mt] = *(const bf16x8*)(As + (wm*64 + mt*16 + l16)*40 + quad*8);
#pragma unroll
      for (int nt = 0; nt < 4; ++nt)
        bw[nt] = *(const bf16x8*)(Bs + (wn*64 + nt*16 + l16)*40 + quad*8);
#pragma unroll
      for (int mt = 0; mt < 4; ++mt)
#pragma unroll
        for (int nt = 0; nt < 4; ++nt)
          acc[mt][nt] = __builtin_amdgcn_mfma_f32_16x16x32_bf16(af[mt], bw[nt], acc[mt][nt], 0, 0, 0);
      __syncthreads();
    }
  }
  // split-K epilogue: accumulate into f32 hid (zero-initialized)
#pragma unroll
  for (int mt = 0; mt < 4; ++mt) {
    const int m = tileM*128 + wm*64 + mt*16 + quad*4;   // D: row = quad*4+reg
#pragma unroll
    for (int nt = 0; nt < 4; ++nt) {
      const int o = o0 + wn*64 + nt*16 + l16;           // D: col = lane&15
#pragma unroll
      for (int r = 0; r < 4; ++r)
        atomicAdd(hidf + (size_t)(m + r)*512 + o, acc[mt][nt][r]);
    }
  }
}

// ---------------- bias + ReLU + bf16 cast ----------------
__global__ __launch_bounds__(256) void k_bias_relu(const float* __restrict__ hidf,
                                                   const float* __restrict__ b1,
                                                   unsigned short* __restrict__ hidb) {
  const int i = blockIdx.x*256 + threadIdx.x;
  const float v = hidf[i] + b1[i & 511];
  hidb[i] = f2bf(fmaxf(v, 0.f));
}

// ---------------- conf+reg heads: GEMM M=4096, N=48 (9 conf + 36 reg + 3 pad), K=512 ----------------
__global__ __launch_bounds__(256) void k_heads(const unsigned short* __restrict__ hid,
                                               const unsigned short* __restrict__ wh,
                                               const float* __restrict__ hb,
                                               float* __restrict__ heads) {
  __shared__ unsigned short As[128*40] __attribute__((aligned(16)));
  __shared__ unsigned short Bs[48*40]  __attribute__((aligned(16)));
  const int t = threadIdx.x, tile = blockIdx.x;
  const int wv = t >> 6, lane = t & 63;
  const int quad = lane >> 4, l16 = lane & 15;
  floatx4 acc[2][3];
#pragma unroll
  for (int mt = 0; mt < 2; ++mt)
#pragma unroll
    for (int nt = 0; nt < 3; ++nt)
      acc[mt][nt] = (floatx4){0.f, 0.f, 0.f, 0.f};
  const int row0 = t >> 2, seg = t & 3;
  for (int c0 = 0; c0 < 512; c0 += 32) {
#pragma unroll
    for (int i = 0; i < 2; ++i) {
      const int row = row0 + (i << 6);
      *(uint4*)(As + row*40 + seg*8) =
          *(const uint4*)(hid + ((size_t)(tile*128 + row))*512 + c0 + seg*8);
    }
    if (t < 192)
      *(uint4*)(Bs + row0*40 + seg*8) =
          *(const uint4*)(wh + (size_t)row0*512 + c0 + seg*8);
    __syncthreads();
    bf16x8 af[2], bw[3];
#pragma unroll
    for (int mt = 0; mt < 2; ++mt)
      af[mt] = *(const bf16x8*)(As + (wv*32 + mt*16 + l16)*40 + quad*8);
#pragma unroll
    for (int nt = 0; nt < 3; ++nt)
      bw[nt] = *(const bf16x8*)(Bs + (nt*16 + l16)*40 + quad*8);
#pragma unroll
    for (int mt = 0; mt < 2; ++mt)
#pragma unroll
      for (int nt = 0; nt < 3; ++nt)
        acc[mt][nt] = __builtin_amdgcn_mfma_f32_16x16x32_bf16(af[mt], bw[nt], acc[mt][nt], 0, 0, 0);
    __syncthreads();
  }
#pragma unroll
  for (int mt = 0; mt < 2; ++mt) {
    const int m = tile*128 + wv*32 + mt*16 + quad*4;
#pragma unroll
    for (int nt = 0; nt < 3; ++nt) {
      const int nn = nt*16 + l16;
      const float bv = hb[nn];
#pragma unroll
      for (int r = 0; r < 4; ++r)
        heads[(size_t)(m + r)*48 + nn] = acc[mt][nt][r] + bv;
    }
  }
}

// ---------------- IoU (strict f32, matches numpy op order) + per-GT max ----------------
__global__ __launch_bounds__(256) void k_iou(const float* __restrict__ gtb,
                                             float* __restrict__ iou,
                                             unsigned int* __restrict__ maxg) {
  const int idx = blockIdx.x*256 + threadIdx.x;     // (b,n)
  const int b = idx / NANC, n = idx - b*NANC;
  const int a = n % 9, pix = n / 9;
  const int xi = pix & 31, yi = pix >> 5;
  const float hw = c_aw[a]*0.5f, hh = c_ah[a]*0.5f;
  const float xc = xi + 0.5f, yc = yi + 0.5f;
  const float x1 = fminf(fmaxf(xc - hw, 0.f), 32.f);
  const float y1 = fminf(fmaxf(yc - hh, 0.f), 32.f);
  const float x2 = fminf(fmaxf(xc + hw, 0.f), 32.f);
  const float y2 = fminf(fmaxf(yc + hh, 0.f), 32.f);
  const float areaA = __fmul_rn(__fsub_rn(x2, x1), __fsub_rn(y2, y1));
  const int lane = threadIdx.x & 63;
  for (int g = 0; g < NG; ++g) {
    const float4 gp = *(const float4*)(gtb + ((size_t)b*NG + g)*4);
    const float gx1 = gp.x * 0.03125f, gy1 = gp.y * 0.03125f;   // /32 exact
    const float gx2 = gp.z * 0.03125f, gy2 = gp.w * 0.03125f;
    const float dx = fmaxf(__fsub_rn(fminf(x2, gx2), fmaxf(x1, gx1)), 0.f);
    const float dy = fmaxf(__fsub_rn(fminf(y2, gy2), fmaxf(y1, gy1)), 0.f);
    const float inter = __fmul_rn(dx, dy);
    const float areaG = __fmul_rn(__fsub_rn(gx2, gx1), __fsub_rn(gy2, gy1));
    const float den = __fadd_rn(__fsub_rn(__fadd_rn(areaA, areaG), inter), 1e-8f);
    const float v = __fdiv_rn(inter, den);
    iou[(size_t)idx*NG + g] = v;
    float m = v;                                     // wave max, then 1 atomic/wave
#pragma unroll
    for (int o = 32; o > 0; o >>= 1) m = fmaxf(m, __shfl_xor(m, o));
    if (lane == 0) atomicMax(&maxg[b*NG + g], __float_as_uint(m));  // iou>=0: bits monotone
  }
}

__device__ __forceinline__ float softplusf(float z) {
  return fmaxf(z, 0.f) + log1pf(expf(-fabsf(z)));
}
__device__ __forceinline__ float sl1f(float d) {
  const float ad = fabsf(d);
  return ad < 1.f ? 0.5f*d*d : ad - 0.5f;
}

// ---------------- assignment, losses, proposals ----------------
__global__ __launch_bounds__(256) void k_assign(const float* __restrict__ iou,
                                                const unsigned int* __restrict__ maxg,
                                                const float* __restrict__ heads,
                                                const float* __restrict__ gtb,
                                                float* __restrict__ out,
                                                float* __restrict__ sums) {
  const int idx = blockIdx.x*256 + threadIdx.x;
  const int b = idx / NANC, n = idx - b*NANC;
  const int a = n % 9, pix = n / 9;
  const int xi = pix & 31, yi = pix >> 5;
  const float hw = c_aw[a]*0.5f, hh = c_ah[a]*0.5f;
  const float xc = xi + 0.5f, yc = yi + 0.5f;
  const float x1 = fminf(fmaxf(xc - hw, 0.f), 32.f);
  const float y1 = fminf(fmaxf(yc - hh, 0.f), 32.f);
  const float x2 = fminf(fmaxf(xc + hw, 0.f), 32.f);
  const float y2 = fminf(fmaxf(yc + hh, 0.f), 32.f);

  const float* irow = iou + (size_t)idx*NG;
  float mx = -1.f; int gi = 0; bool pos = false;
  for (int g = 0; g < NG; ++g) {
    const float v = irow[g];
    const float mg = __uint_as_float(maxg[b*NG + g]);
    pos = pos || (v > 0.7f) || ((v == mg) && (mg > 1e-8f));
    if (v > mx) { mx = v; gi = g; }                  // first-max argmax
  }
  const bool neg = (mx < 0.3f) && !pos;
  const float posf = pos ? 1.f : 0.f;

  const int m = b*1024 + pix;
  const float* hrow = heads + (size_t)m*48;
  const float conf = hrow[a];
  const float of0 = hrow[9 + a*4 + 0];
  const float of1 = hrow[9 + a*4 + 1];
  const float of2 = hrow[9 + a*4 + 2];
  const float of3 = hrow[9 + a*4 + 3];

  float cls = 0.f;
  if (pos) cls = softplusf(-conf);
  else if (neg) cls = softplusf(conf);

  const float acx = (x1 + x2)*0.5f, acy = (y1 + y2)*0.5f;
  const float aw = x2 - x1, ah = y2 - y1;
  float reg = 0.f;
  if (pos) {
    const float4 gp = *(const float4*)(gtb + ((size_t)b*NG + gi)*4);
    const float gx1 = gp.x*0.03125f, gy1 = gp.y*0.03125f;
    const float gx2 = gp.z*0.03125f, gy2 = gp.w*0.03125f;
    const float gcx = (gx1+gx2)*0.5f, gcy = (gy1+gy2)*0.5f;
    const float gw = gx2-gx1, gh = gy2-gy1;
    const float t0 = (gcx-acx)/(aw+1e-8f), t1 = (gcy-acy)/(ah+1e-8f);
    const float t2 = logf((gw+1e-8f)/(aw+1e-8f)), t3 = logf((gh+1e-8f)/(ah+1e-8f));
    reg = sl1f(of0-t0) + sl1f(of1-t1) + sl1f(of2-t2) + sl1f(of3-t3);
  }

  const float pcx = acx + of0*aw, pcy = acy + of1*ah;
  const float pw = aw*expf(of2), ph = ah*expf(of3);
  float* op = out + 1 + (size_t)idx*4;               // out+1 not 16B aligned: scalar stores
  op[0] = (pcx - pw*0.5f)*posf;
  op[1] = (pcy - ph*0.5f)*posf;
  op[2] = (pcx + pw*0.5f)*posf;
  op[3] = (pcy + ph*0.5f)*posf;
  out[1 + 4*(size_t)NB*NANC + idx] = posf;

  float cs = cls, rs = reg;
#pragma unroll
  for (int o = 32; o > 0; o >>= 1) { cs += __shfl_xor(cs, o); rs += __shfl_xor(rs, o); }
  if ((threadIdx.x & 63) == 0) { atomicAdd(&sums[0], cs); atomicAdd(&sums[1], rs); }
}

__global__ void k_finalize(const float* __restrict__ sums, float* __restrict__ out) {
  if (threadIdx.x == 0 && blockIdx.x == 0)
    out[0] = sums[0]*0.25f + 5.f*(sums[1]*0.25f);    // w_conf*cls/B + w_reg*reg/B
}

extern "C" void kernel_launch(void* const* d_in, const int* in_sizes, int n_in,
                              void* d_out, int out_size, void* d_ws, size_t ws_size,
                              hipStream_t stream) {
  const float* x   = (const float*)d_in[0];
  const float* gtb = (const float*)d_in[1];
  // d_in[2] = gt_classes (unused by the loss)
  const float* w1  = (const float*)d_in[3];
  const float* b1  = (const float*)d_in[4];
  const float* cw  = (const float*)d_in[5];
  const float* cb  = (const float*)d_in[6];
  const float* rw  = (const float*)d_in[7];
  const float* rb  = (const float*)d_in[8];
  float* out = (float*)d_out;
  char* ws = (char*)d_ws;

  unsigned short* xh    = (unsigned short*)(ws + OFF_XH);
  unsigned short* wt    = (unsigned short*)(ws + OFF_WT);
  float*          hidf  = (float*)(ws + OFF_HIDF);
  unsigned short* hidb  = (unsigned short*)(ws + OFF_HIDB);
  unsigned short* wh    = (unsigned short*)(ws + OFF_WH);
  float*          hb    = (float*)(ws + OFF_HB);
  float*          heads = (float*)(ws + OFF_HEADS);
  float*          iou   = (float*)(ws + OFF_IOU);
  unsigned int*   maxg  = (unsigned int*)(ws + OFF_MAXG);
  float*          sums  = (float*)(ws + OFF_SUMS);

  hipMemsetAsync(hidf, 0, (size_t)NM*NHID*sizeof(float), stream);   // split-K accumulator
  hipMemsetAsync(ws + OFF_MAXG, 0, 1024, stream);                   // maxg + sums

  k_transpose_x<<<dim3(64, 32, 4), dim3(32, 8), 0, stream>>>(x, xh);
  k_transpose_w<<<4096, 256, 0, stream>>>(w1, wt);
  k_build_wh<<<96, 256, 0, stream>>>(cw, cb, rw, rb, wh, hb);
  k_conv_gemm<<<dim3(32, 4, 2), 256, 0, stream>>>(xh, wt, hidf);
  k_bias_relu<<<8192, 256, 0, stream>>>(hidf, b1, hidb);
  k_heads<<<32, 256, 0, stream>>>(hidb, wh, hb, heads);
  k_iou<<<144, 256, 0, stream>>>(gtb, iou, maxg);
  k_assign<<<144, 256, 0, stream>>>(iou, maxg, heads, gtb, out, sums);
  k_finalize<<<1, 64, 0, stream>>>(sums, out);
}

// Round 2
// 326.491 us; speedup vs baseline: 1.2759x; 1.2759x over previous
//
#include <hip/hip_runtime.h>

// RPN forward on gfx950. Heavy op = 3x3 conv (2048->512) = 77.3 GFLOP -> bf16 MFMA.
// R1: halo-padded input + global_load_lds(16B) staging + seg-swizzled LDS +
//     split-K (runtime 1/2/4/8 by ws_size) with private f32 partials (no atomics).
// pos/neg assignment in strict IEEE f32 (no contraction) to bit-match numpy ref.

typedef __bf16 bf16x8 __attribute__((ext_vector_type(8)));
typedef float floatx4 __attribute__((ext_vector_type(4)));

#define NB 4
#define NC 2048
#define NH 32
#define NW 32
#define NHID 512
#define NA 9
#define NG 20
#define NANC 9216            // NH*NW*NA
#define NM 4096              // NB*NH*NW

// workspace layout (bytes); hidp (split-K partials) last so nsplit can shrink to fit
#define OFF_XH    0ull            // [4][34][34][2048] bf16 (zero halo) = 18939904
#define OFF_WT    18939904ull     // [9][512][2048]    bf16 = 18874368
#define OFF_HIDB  37814272ull     // [4096][512]       bf16 =  4194304
#define OFF_WH    42008576ull     // [48][512]         bf16 =    49152
#define OFF_HB    42057728ull     // [48]              f32  (pad 256)
#define OFF_HEADS 42057984ull     // [4096][48]        f32  =   786432
#define OFF_IOU   42844416ull     // [4*9216][20]      f32  =  2949120
#define OFF_MAXG  45793536ull     // [4][20] uint bits (pad 512)
#define OFF_SUMS  45794048ull     // [2] f32 (pad 256)
#define OFF_HIDP  45794304ull     // [nsplit][4096][512] f32, 8388608 each

__device__ __forceinline__ unsigned short f2bf(float f) {
  unsigned int u = __float_as_uint(f);
  u = (u + 0x7fffu + ((u >> 16) & 1u)) >> 16;   // RNE
  return (unsigned short)u;
}

// async global->LDS, 16B/lane; LDS dest = wave-uniform base + lane*16
__device__ __forceinline__ void gload16(const void* g, void* l) {
  __builtin_amdgcn_global_load_lds(
      (const __attribute__((address_space(1))) unsigned int*)g,
      (__attribute__((address_space(3))) unsigned int*)l, 16, 0, 0);
}

// anchor widths/heights: aw = repeat([2,4,6],3); ah = (scale*ratio) flattened
__constant__ float c_aw[9] = {2.f,2.f,2.f,4.f,4.f,4.f,6.f,6.f,6.f};
__constant__ float c_ah[9] = {1.f,2.f,3.f,2.f,4.f,6.f,3.f,6.f,9.f};

// ---------------- x: NCHW f32 -> halo NHWC bf16 ----------------
__global__ __launch_bounds__(256) void k_transpose_x(const float* __restrict__ x,
                                                     unsigned short* __restrict__ xh) {
  __shared__ float tile[32][33];
  const int c0 = blockIdx.x << 5;
  const int h  = blockIdx.y;
  const int b  = blockIdx.z;
  const int tx = threadIdx.x, ty = threadIdx.y;
  const float* src = x + (((size_t)b*NC + c0)*NH + h)*NW;
#pragma unroll
  for (int j = 0; j < 4; ++j) {
    const int c = ty + j*8;
    tile[c][tx] = src[(size_t)c*NH*NW + tx];
  }
  __syncthreads();
  // interior of halo: xh[b][h+1][w+1][c]
  unsigned short* dst = xh + ((size_t)(b*34 + h + 1)*34 + 1)*2048 + c0;
#pragma unroll
  for (int j = 0; j < 4; ++j) {
    const int w = ty + j*8;
    dst[(size_t)w*2048 + tx] = f2bf(tile[tx][w]);
  }
}

// ---------------- w1: [O][C][3][3] f32 -> [g][O][C] bf16 ----------------
__global__ __launch_bounds__(256) void k_transpose_w(const float* __restrict__ w1,
                                                     unsigned short* __restrict__ wt) {
  const int t = blockIdx.x * 256 + threadIdx.x;   // t = o*2048 + c
  const float* src = w1 + (size_t)t * 9;          // 9 contiguous taps
#pragma unroll
  for (int g = 0; g < 9; ++g)
    wt[(size_t)g*NHID*NC + t] = f2bf(src[g]);
}

// ---------------- head weights -> [48][512] bf16 + bias[48] ----------------
__global__ __launch_bounds__(256) void k_build_wh(const float* __restrict__ cw, const float* __restrict__ cb,
                                                  const float* __restrict__ rw, const float* __restrict__ rb,
                                                  unsigned short* __restrict__ wh, float* __restrict__ hb) {
  const int t = blockIdx.x*256 + threadIdx.x;     // 0..48*512-1
  const int n = t >> 9, c = t & 511;
  float v = 0.f;
  if (n < 9) v = cw[n*512 + c];
  else if (n < 45) v = rw[(n-9)*512 + c];
  wh[t] = f2bf(v);
  if (c == 0) {
    float bv = 0.f;
    if (n < 9) bv = cb[n];
    else if (n < 45) bv = rb[n-9];
    hb[n] = bv;
  }
}

// ---------------- conv 3x3 as implicit GEMM, bf16 MFMA ----------------
// M=4096, N=512, K=9*2048. Tile 128x128, BK=32. Grid (32,4,nsplit); split over c.
// Staging via global_load_lds 16B/lane into unpadded LDS [row][32] shorts with
// seg swizzle pos=(seg+row+(row>>2))&3 -> b128 fragment reads are 2-way (free).
__global__ __launch_bounds__(256) void k_conv_gemm(const unsigned short* __restrict__ xh,
                                                   const unsigned short* __restrict__ wt,
                                                   float* __restrict__ hidp, int csplit) {
  __shared__ unsigned short As[128*32] __attribute__((aligned(16)));   // 8 KB
  __shared__ unsigned short Bs[128*32] __attribute__((aligned(16)));   // 8 KB
  const int t = threadIdx.x;
  const int tileM = blockIdx.x, tileN = blockIdx.y, kz = blockIdx.z;
  const int b = tileM >> 3, h0 = (tileM & 7) << 2;
  const int o0 = tileN << 7;
  const int wv = t >> 6, lane = t & 63;
  const int wm = wv >> 1, wn = wv & 1;
  const int quad = lane >> 4, l16 = lane & 15;
  const int c_base = kz * csplit;

  floatx4 acc[4][4];
#pragma unroll
  for (int mt = 0; mt < 4; ++mt)
#pragma unroll
    for (int nt = 0; nt < 4; ++nt)
      acc[mt][nt] = (floatx4){0.f, 0.f, 0.f, 0.f};

  // staging geometry: per wave 2 instrs for A (32 rows) + 2 for B
  const int lrow = lane >> 2, spos = lane & 3;
  size_t gA[2], gB[2];
#pragma unroll
  for (int j = 0; j < 2; ++j) {
    const int row = wv*32 + j*16 + lrow;
    const int sd = (spos - row - (row >> 2)) & 3;      // logical seg this lane fetches
    const int hh = h0 + (row >> 5) + 1, ww = (row & 31) + 1;
    gA[j] = ((size_t)((b*34 + hh)*34 + ww))*2048 + c_base + sd*8;
    gB[j] = ((size_t)(o0 + row))*2048 + c_base + sd*8;
  }
  unsigned short* ldsA0 = As + (wv*32)*32;
  unsigned short* ldsA1 = As + (wv*32 + 16)*32;
  unsigned short* ldsB0 = Bs + (wv*32)*32;
  unsigned short* ldsB1 = Bs + (wv*32 + 16)*32;

  // fragment-read swizzle position (same for all mt/nt: row%4=l16%4, (row>>2)%4=(l16>>2)%4)
  const int pA = (quad + (l16 & 3) + ((l16 >> 2) & 3)) & 3;

  for (int g = 0; g < 9; ++g) {
    const ptrdiff_t dsp = (ptrdiff_t)((g/3 - 1)*34 + (g%3 - 1)) * 2048;
    const unsigned short* wgp = wt + (size_t)g*NHID*NC;
    for (int c0 = 0; c0 < csplit; c0 += 32) {
      gload16(xh + gA[0] + dsp + c0, ldsA0);
      gload16(xh + gA[1] + dsp + c0, ldsA1);
      gload16(wgp + gB[0] + c0, ldsB0);
      gload16(wgp + gB[1] + c0, ldsB1);
      __syncthreads();
      bf16x8 af[4], bw[4];
#pragma unroll
      for (int mt = 0; mt < 4; ++mt)
        af[mt] = *(const bf16x8*)(As + (wm*64 + mt*16 + l16)*32 + pA*8);
#pragma unroll
      for (int nt = 0; nt < 4; ++nt)
        bw[nt] = *(const bf16x8*)(Bs + (wn*64 + nt*16 + l16)*32 + pA*8);
#pragma unroll
      for (int mt = 0; mt < 4; ++mt)
#pragma unroll
        for (int nt = 0; nt < 4; ++nt)
          acc[mt][nt] = __builtin_amdgcn_mfma_f32_16x16x32_bf16(af[mt], bw[nt], acc[mt][nt], 0, 0, 0);
      __syncthreads();
    }
  }
  // private split-K partial: plain stores, no atomics
  float* hp = hidp + (size_t)kz*NM*NHID;
#pragma unroll
  for (int mt = 0; mt < 4; ++mt) {
    const int m = tileM*128 + wm*64 + mt*16 + quad*4;   // D: row = quad*4+reg
#pragma unroll
    for (int nt = 0; nt < 4; ++nt) {
      const int o = o0 + wn*64 + nt*16 + l16;           // D: col = lane&15
#pragma unroll
      for (int r = 0; r < 4; ++r)
        hp[(size_t)(m + r)*NHID + o] = acc[mt][nt][r];
    }
  }
}

// ---------------- split-K reduce + bias + ReLU + bf16 cast ----------------
__global__ __launch_bounds__(256) void k_reduce(const float* __restrict__ hidp,
                                                const float* __restrict__ b1,
                                                unsigned short* __restrict__ hidb, int nsplit) {
  const int i4 = (blockIdx.x*256 + threadIdx.x) * 4;
  float4 s = *(const float4*)(hidp + i4);
  for (int sp = 1; sp < nsplit; ++sp) {
    const float4 v = *(const float4*)(hidp + (size_t)sp*NM*NHID + i4);
    s.x += v.x; s.y += v.y; s.z += v.z; s.w += v.w;
  }
  const float4 bb = *(const float4*)(b1 + (i4 & 511));
  union { unsigned short u[4]; uint2 v; } r;
  r.u[0] = f2bf(fmaxf(s.x + bb.x, 0.f));
  r.u[1] = f2bf(fmaxf(s.y + bb.y, 0.f));
  r.u[2] = f2bf(fmaxf(s.z + bb.z, 0.f));
  r.u[3] = f2bf(fmaxf(s.w + bb.w, 0.f));
  *(uint2*)(hidb + i4) = r.v;
}

// ---------------- conf+reg heads: GEMM M=4096, N=48, K=512, tile 64 rows ----------------
__global__ __launch_bounds__(256) void k_heads(const unsigned short* __restrict__ hid,
                                               const unsigned short* __restrict__ wh,
                                               const float* __restrict__ hb,
                                               float* __restrict__ heads) {
  __shared__ unsigned short As[64*40] __attribute__((aligned(16)));
  __shared__ unsigned short Bs[48*40] __attribute__((aligned(16)));
  const int t = threadIdx.x, tile = blockIdx.x;     // 64 tiles of 64 rows
  const int wv = t >> 6, lane = t & 63;
  const int quad = lane >> 4, l16 = lane & 15;
  floatx4 acc[3];
#pragma unroll
  for (int nt = 0; nt < 3; ++nt) acc[nt] = (floatx4){0.f, 0.f, 0.f, 0.f};
  const int row0 = t >> 2, seg = t & 3;
  for (int c0 = 0; c0 < 512; c0 += 32) {
    *(uint4*)(As + row0*40 + seg*8) =
        *(const uint4*)(hid + ((size_t)(tile*64 + row0))*512 + c0 + seg*8);
    if (t < 192)
      *(uint4*)(Bs + row0*40 + seg*8) =
          *(const uint4*)(wh + (size_t)row0*512 + c0 + seg*8);
    __syncthreads();
    const bf16x8 af = *(const bf16x8*)(As + (wv*16 + l16)*40 + quad*8);
#pragma unroll
    for (int nt = 0; nt < 3; ++nt) {
      const bf16x8 bw = *(const bf16x8*)(Bs + (nt*16 + l16)*40 + quad*8);
      acc[nt] = __builtin_amdgcn_mfma_f32_16x16x32_bf16(af, bw, acc[nt], 0, 0, 0);
    }
    __syncthreads();
  }
  const int m = tile*64 + wv*16 + quad*4;
#pragma unroll
  for (int nt = 0; nt < 3; ++nt) {
    const int nn = nt*16 + l16;
    const float bv = hb[nn];
#pragma unroll
    for (int r = 0; r < 4; ++r)
      heads[(size_t)(m + r)*48 + nn] = acc[nt][r] + bv;
  }
}

// ---------------- IoU (strict f32, matches numpy op order) + per-GT max ----------------
__global__ __launch_bounds__(256) void k_iou(const float* __restrict__ gtb,
                                             float* __restrict__ iou,
                                             unsigned int* __restrict__ maxg) {
  const int idx = blockIdx.x*256 + threadIdx.x;     // (b,n)
  const int b = idx / NANC, n = idx - b*NANC;
  const int a = n % 9, pix = n / 9;
  const int xi = pix & 31, yi = pix >> 5;
  const float hw = c_aw[a]*0.5f, hh = c_ah[a]*0.5f;
  const float xc = xi + 0.5f, yc = yi + 0.5f;
  const float x1 = fminf(fmaxf(xc - hw, 0.f), 32.f);
  const float y1 = fminf(fmaxf(yc - hh, 0.f), 32.f);
  const float x2 = fminf(fmaxf(xc + hw, 0.f), 32.f);
  const float y2 = fminf(fmaxf(yc + hh, 0.f), 32.f);
  const float areaA = __fmul_rn(__fsub_rn(x2, x1), __fsub_rn(y2, y1));
  const int lane = threadIdx.x & 63;
  for (int g = 0; g < NG; ++g) {
    const float4 gp = *(const float4*)(gtb + ((size_t)b*NG + g)*4);
    const float gx1 = gp.x * 0.03125f, gy1 = gp.y * 0.03125f;   // /32 exact
    const float gx2 = gp.z * 0.03125f, gy2 = gp.w * 0.03125f;
    const float dx = fmaxf(__fsub_rn(fminf(x2, gx2), fmaxf(x1, gx1)), 0.f);
    const float dy = fmaxf(__fsub_rn(fminf(y2, gy2), fmaxf(y1, gy1)), 0.f);
    const float inter = __fmul_rn(dx, dy);
    const float areaG = __fmul_rn(__fsub_rn(gx2, gx1), __fsub_rn(gy2, gy1));
    const float den = __fadd_rn(__fsub_rn(__fadd_rn(areaA, areaG), inter), 1e-8f);
    const float v = __fdiv_rn(inter, den);
    iou[(size_t)idx*NG + g] = v;
    float m = v;                                     // wave max, then 1 atomic/wave
#pragma unroll
    for (int o = 32; o > 0; o >>= 1) m = fmaxf(m, __shfl_xor(m, o));
    if (lane == 0) atomicMax(&maxg[b*NG + g], __float_as_uint(m));  // iou>=0: bits monotone
  }
}

__device__ __forceinline__ float softplusf(float z) {
  return fmaxf(z, 0.f) + log1pf(expf(-fabsf(z)));
}
__device__ __forceinline__ float sl1f(float d) {
  const float ad = fabsf(d);
  return ad < 1.f ? 0.5f*d*d : ad - 0.5f;
}

// ---------------- assignment, losses, proposals ----------------
__global__ __launch_bounds__(256) void k_assign(const float* __restrict__ iou,
                                                const unsigned int* __restrict__ maxg,
                                                const float* __restrict__ heads,
                                                const float* __restrict__ gtb,
                                                float* __restrict__ out,
                                                float* __restrict__ sums) {
  const int idx = blockIdx.x*256 + threadIdx.x;
  const int b = idx / NANC, n = idx - b*NANC;
  const int a = n % 9, pix = n / 9;
  const int xi = pix & 31, yi = pix >> 5;
  const float hw = c_aw[a]*0.5f, hh = c_ah[a]*0.5f;
  const float xc = xi + 0.5f, yc = yi + 0.5f;
  const float x1 = fminf(fmaxf(xc - hw, 0.f), 32.f);
  const float y1 = fminf(fmaxf(yc - hh, 0.f), 32.f);
  const float x2 = fminf(fmaxf(xc + hw, 0.f), 32.f);
  const float y2 = fminf(fmaxf(yc + hh, 0.f), 32.f);

  const float* irow = iou + (size_t)idx*NG;
  float mx = -1.f; int gi = 0; bool pos = false;
  for (int g = 0; g < NG; ++g) {
    const float v = irow[g];
    const float mg = __uint_as_float(maxg[b*NG + g]);
    pos = pos || (v > 0.7f) || ((v == mg) && (mg > 1e-8f));
    if (v > mx) { mx = v; gi = g; }                  // first-max argmax
  }
  const bool neg = (mx < 0.3f) && !pos;
  const float posf = pos ? 1.f : 0.f;

  const int m = b*1024 + pix;
  const float* hrow = heads + (size_t)m*48;
  const float conf = hrow[a];
  const float of0 = hrow[9 + a*4 + 0];
  const float of1 = hrow[9 + a*4 + 1];
  const float of2 = hrow[9 + a*4 + 2];
  const float of3 = hrow[9 + a*4 + 3];

  float cls = 0.f;
  if (pos) cls = softplusf(-conf);
  else if (neg) cls = softplusf(conf);

  const float acx = (x1 + x2)*0.5f, acy = (y1 + y2)*0.5f;
  const float aw = x2 - x1, ah = y2 - y1;
  float reg = 0.f;
  if (pos) {
    const float4 gp = *(const float4*)(gtb + ((size_t)b*NG + gi)*4);
    const float gx1 = gp.x*0.03125f, gy1 = gp.y*0.03125f;
    const float gx2 = gp.z*0.03125f, gy2 = gp.w*0.03125f;
    const float gcx = (gx1+gx2)*0.5f, gcy = (gy1+gy2)*0.5f;
    const float gw = gx2-gx1, gh = gy2-gy1;
    const float t0 = (gcx-acx)/(aw+1e-8f), t1 = (gcy-acy)/(ah+1e-8f);
    const float t2 = logf((gw+1e-8f)/(aw+1e-8f)), t3 = logf((gh+1e-8f)/(ah+1e-8f));
    reg = sl1f(of0-t0) + sl1f(of1-t1) + sl1f(of2-t2) + sl1f(of3-t3);
  }

  const float pcx = acx + of0*aw, pcy = acy + of1*ah;
  const float pw = aw*expf(of2), ph = ah*expf(of3);
  float* op = out + 1 + (size_t)idx*4;               // out+1 not 16B aligned: scalar stores
  op[0] = (pcx - pw*0.5f)*posf;
  op[1] = (pcy - ph*0.5f)*posf;
  op[2] = (pcx + pw*0.5f)*posf;
  op[3] = (pcy + ph*0.5f)*posf;
  out[1 + 4*(size_t)NB*NANC + idx] = posf;

  float cs = cls, rs = reg;
#pragma unroll
  for (int o = 32; o > 0; o >>= 1) { cs += __shfl_xor(cs, o); rs += __shfl_xor(rs, o); }
  if ((threadIdx.x & 63) == 0) { atomicAdd(&sums[0], cs); atomicAdd(&sums[1], rs); }
}

__global__ void k_finalize(const float* __restrict__ sums, float* __restrict__ out) {
  if (threadIdx.x == 0 && blockIdx.x == 0)
    out[0] = sums[0]*0.25f + 5.f*(sums[1]*0.25f);    // w_conf*cls/B + w_reg*reg/B
}

extern "C" void kernel_launch(void* const* d_in, const int* in_sizes, int n_in,
                              void* d_out, int out_size, void* d_ws, size_t ws_size,
                              hipStream_t stream) {
  const float* x   = (const float*)d_in[0];
  const float* gtb = (const float*)d_in[1];
  // d_in[2] = gt_classes (unused by the loss)
  const float* w1  = (const float*)d_in[3];
  const float* b1  = (const float*)d_in[4];
  const float* cw  = (const float*)d_in[5];
  const float* cb  = (const float*)d_in[6];
  const float* rw  = (const float*)d_in[7];
  const float* rb  = (const float*)d_in[8];
  float* out = (float*)d_out;
  char* ws = (char*)d_ws;

  unsigned short* xh    = (unsigned short*)(ws + OFF_XH);
  unsigned short* wt    = (unsigned short*)(ws + OFF_WT);
  unsigned short* hidb  = (unsigned short*)(ws + OFF_HIDB);
  unsigned short* wh    = (unsigned short*)(ws + OFF_WH);
  float*          hb    = (float*)(ws + OFF_HB);
  float*          heads = (float*)(ws + OFF_HEADS);
  float*          iou   = (float*)(ws + OFF_IOU);
  unsigned int*   maxg  = (unsigned int*)(ws + OFF_MAXG);
  float*          sums  = (float*)(ws + OFF_SUMS);
  float*          hidp  = (float*)(ws + OFF_HIDP);

  // split-K factor sized to available workspace (8 -> 1024 blocks = 4/CU)
  int nsplit = 8;
  while (nsplit > 1 && OFF_HIDP + (size_t)nsplit*NM*NHID*4 > ws_size) nsplit >>= 1;
  const int csplit = NC / nsplit;

  hipMemsetAsync(xh, 0, OFF_WT - OFF_XH, stream);        // zero halo (interior overwritten)
  hipMemsetAsync(ws + OFF_MAXG, 0, 768, stream);         // maxg + sums

  k_transpose_x<<<dim3(64, 32, 4), dim3(32, 8), 0, stream>>>(x, xh);
  k_transpose_w<<<4096, 256, 0, stream>>>(w1, wt);
  k_build_wh<<<96, 256, 0, stream>>>(cw, cb, rw, rb, wh, hb);
  k_conv_gemm<<<dim3(32, 4, nsplit), 256, 0, stream>>>(xh, wt, hidp, csplit);
  k_reduce<<<2048, 256, 0, stream>>>(hidp, b1, hidb, nsplit);
  k_heads<<<64, 256, 0, stream>>>(hidb, wh, hb, heads);
  k_iou<<<144, 256, 0, stream>>>(gtb, iou, maxg);
  k_assign<<<144, 256, 0, stream>>>(iou, maxg, heads, gtb, out, sums);
  k_finalize<<<1, 64, 0, stream>>>(sums, out);
}

// Round 3
// 287.758 us; speedup vs baseline: 1.4477x; 1.1346x over previous
//
#include <hip/hip_runtime.h>

// RPN forward on gfx950. Heavy op = 3x3 conv (2048->512) = 77.3 GFLOP -> bf16 MFMA.
// R2: BK=64 conv (32KB LDS, 4 blocks/CU), 8-pos seg swizzle, bf16 split-K partials,
//     iou array eliminated (recompute, bit-identical strict f32), fused tail kernels.

typedef __bf16 bf16x8 __attribute__((ext_vector_type(8)));
typedef float floatx4 __attribute__((ext_vector_type(4)));

#define NB 4
#define NC 2048
#define NH 32
#define NW 32
#define NHID 512
#define NA 9
#define NG 20
#define NANC 9216            // NH*NW*NA
#define NM 4096              // NB*NH*NW

// workspace layout (bytes)
#define OFF_XH    0ull            // [4][34][34][2048] bf16 (zero halo) = 18939904
#define OFF_WT    18939904ull     // [9][512][2048]    bf16 = 18874368
#define OFF_HIDB  37814272ull     // [4096][512]       bf16 =  4194304
#define OFF_WH    42008576ull     // [48][512]         bf16 =    49152
#define OFF_HB    42057728ull     // [48]              f32  (pad 256)
#define OFF_HEADS 42057984ull     // [4096][48]        f32  =   786432
#define OFF_MAXG  42844416ull     // [4][20] uint bits (pad 512)
#define OFF_SUMS  42844928ull     // [2] f32 (pad 128)
#define OFF_CTR   42845056ull     // [1] uint (pad 128)
#define OFF_HIDP  42845184ull     // [nsplit][4096][512] bf16, 4194304 each

__device__ __forceinline__ unsigned short f2bf(float f) {
  unsigned int u = __float_as_uint(f);
  u = (u + 0x7fffu + ((u >> 16) & 1u)) >> 16;   // RNE
  return (unsigned short)u;
}

// async global->LDS, 16B/lane; LDS dest = wave-uniform base + lane*16
__device__ __forceinline__ void gload16(const void* g, void* l) {
  __builtin_amdgcn_global_load_lds(
      (const __attribute__((address_space(1))) unsigned int*)g,
      (__attribute__((address_space(3))) unsigned int*)l, 16, 0, 0);
}

// anchor widths/heights: aw = repeat([2,4,6],3); ah = (scale*ratio) flattened
__constant__ float c_aw[9] = {2.f,2.f,2.f,4.f,4.f,4.f,6.f,6.f,6.f};
__constant__ float c_ah[9] = {1.f,2.f,3.f,2.f,4.f,6.f,3.f,6.f,9.f};

// ---- shared strict-f32 anchor/IoU helpers (must be bit-identical in both kernels) ----
struct Anc { float x1, y1, x2, y2, areaA; };
__device__ __forceinline__ Anc anc_of(int n) {
  const int a = n % 9, pix = n / 9;
  const int xi = pix & 31, yi = pix >> 5;
  const float hw = c_aw[a]*0.5f, hh = c_ah[a]*0.5f;
  const float xc = xi + 0.5f, yc = yi + 0.5f;
  Anc A;
  A.x1 = fminf(fmaxf(xc - hw, 0.f), 32.f);
  A.y1 = fminf(fmaxf(yc - hh, 0.f), 32.f);
  A.x2 = fminf(fmaxf(xc + hw, 0.f), 32.f);
  A.y2 = fminf(fmaxf(yc + hh, 0.f), 32.f);
  A.areaA = __fmul_rn(__fsub_rn(A.x2, A.x1), __fsub_rn(A.y2, A.y1));
  return A;
}
__device__ __forceinline__ float iou_one(const Anc& A, float4 gp) {
  const float gx1 = gp.x * 0.03125f, gy1 = gp.y * 0.03125f;   // /32 exact
  const float gx2 = gp.z * 0.03125f, gy2 = gp.w * 0.03125f;
  const float dx = fmaxf(__fsub_rn(fminf(A.x2, gx2), fmaxf(A.x1, gx1)), 0.f);
  const float dy = fmaxf(__fsub_rn(fminf(A.y2, gy2), fmaxf(A.y1, gy1)), 0.f);
  const float inter = __fmul_rn(dx, dy);
  const float areaG = __fmul_rn(__fsub_rn(gx2, gx1), __fsub_rn(gy2, gy1));
  const float den = __fadd_rn(__fsub_rn(__fadd_rn(A.areaA, areaG), inter), 1e-8f);
  return __fdiv_rn(inter, den);
}

// ---------------- x: NCHW f32 -> halo NHWC bf16 (packed 4B stores) ----------------
__global__ __launch_bounds__(256) void k_transpose_x(const float* __restrict__ x,
                                                     unsigned short* __restrict__ xh) {
  __shared__ float tile[64][33];
  const int c0 = blockIdx.x << 6;
  const int h  = blockIdx.y;
  const int b  = blockIdx.z;
  const int tid = threadIdx.x;
  const int w = tid & 31, cl = tid >> 5;
  const float* src = x + (((size_t)b*NC + c0)*NH + h)*NW;
#pragma unroll
  for (int j = 0; j < 8; ++j) {
    const int c = cl + j*8;
    tile[c][w] = src[(size_t)c*NH*NW + w];
  }
  __syncthreads();
  unsigned short* dst = xh + ((size_t)(b*34 + h + 1)*34 + 1)*2048 + c0;
  const int c2 = (tid & 31)*2, wr = tid >> 5;
#pragma unroll
  for (int j = 0; j < 4; ++j) {
    const int ww = wr + j*8;
    const unsigned int lo = f2bf(tile[c2][ww]), hi = f2bf(tile[c2+1][ww]);
    *(unsigned int*)(dst + (size_t)ww*2048 + c2) = lo | (hi << 16);
  }
}

// ---------------- w1 -> [g][O][C] bf16; fused head-weight prep ----------------
__global__ __launch_bounds__(256) void k_prep_w(const float* __restrict__ w1,
                                                unsigned short* __restrict__ wt,
                                                const float* __restrict__ cw, const float* __restrict__ cb,
                                                const float* __restrict__ rw, const float* __restrict__ rb,
                                                unsigned short* __restrict__ wh, float* __restrict__ hb) {
  const int bid = blockIdx.x;
  if (bid >= 4096) {          // head-weight blocks
    const int t = (bid - 4096)*256 + threadIdx.x;    // 0..24575
    const int n = t >> 9, c = t & 511;
    float v = 0.f;
    if (n < 9) v = cw[n*512 + c];
    else if (n < 45) v = rw[(n-9)*512 + c];
    wh[t] = f2bf(v);
    if (c == 0) {
      float bv = 0.f;
      if (n < 9) bv = cb[n];
      else if (n < 45) bv = rb[n-9];
      hb[n] = bv;
    }
    return;
  }
  const int t = bid*256 + threadIdx.x;    // t = o*2048 + c
  const float* src = w1 + (size_t)t * 9;  // 9 contiguous taps
#pragma unroll
  for (int g = 0; g < 9; ++g)
    wt[(size_t)g*NHID*NC + t] = f2bf(src[g]);
}

// ---------------- conv 3x3 as implicit GEMM, bf16 MFMA ----------------
// M=4096, N=512, K=9*2048. Tile 128x128, BK=64 (32 MFMA per barrier). Grid (32,4,nsplit).
// global_load_lds 16B/lane; seg swizzle: logical 16B-seg s of row r stored at pos (s+r)&7
// -> each b128 fragment read covers all 8 bank-quads (8 lanes each) = minimum cycles.
__global__ __launch_bounds__(256, 4) void k_conv_gemm(const unsigned short* __restrict__ xh,
                                                      const unsigned short* __restrict__ wt,
                                                      unsigned short* __restrict__ hidp, int csplit) {
  __shared__ unsigned short As[128*64] __attribute__((aligned(16)));   // 16 KB
  __shared__ unsigned short Bs[128*64] __attribute__((aligned(16)));   // 16 KB
  const int t = threadIdx.x;
  const int tileM = blockIdx.x, tileN = blockIdx.y, kz = blockIdx.z;
  const int b = tileM >> 3, h0 = (tileM & 7) << 2;
  const int o0 = tileN << 7;
  const int wv = t >> 6, lane = t & 63;
  const int wm = wv >> 1, wn = wv & 1;
  const int quad = lane >> 4, l16 = lane & 15;
  const int c_base = kz * csplit;

  floatx4 acc[4][4];
#pragma unroll
  for (int mt = 0; mt < 4; ++mt)
#pragma unroll
    for (int nt = 0; nt < 4; ++nt)
      acc[mt][nt] = (floatx4){0.f, 0.f, 0.f, 0.f};

  // staging geometry: 4 instrs each for A/B per wave; instr j covers 8 rows (128B each)
  const int lr = lane >> 3, pos = lane & 7;
  int gA[4], gB[4];                                   // short-index offsets (32-bit ok)
#pragma unroll
  for (int j = 0; j < 4; ++j) {
    const int row = wv*32 + j*8 + lr;
    const int sd = (pos - row) & 7;                   // logical seg this lane fetches
    const int hh = h0 + (row >> 5) + 1, ww = (row & 31) + 1;
    gA[j] = ((b*34 + hh)*34 + ww)*2048 + c_base + sd*8;
    gB[j] = (o0 + row)*2048 + c_base + sd*8;
  }

  for (int g = 0; g < 9; ++g) {
    const int dsp = ((g/3 - 1)*34 + (g%3 - 1)) * 2048;
    const unsigned short* wgp = wt + (size_t)g*NHID*NC;
    for (int c0 = 0; c0 < csplit; c0 += 64) {
#pragma unroll
      for (int j = 0; j < 4; ++j) {
        gload16(xh + gA[j] + dsp + c0, As + (wv*32 + j*8)*64);
        gload16(wgp + gB[j] + c0,      Bs + (wv*32 + j*8)*64);
      }
      __syncthreads();
#pragma unroll
      for (int sub = 0; sub < 2; ++sub) {
        const int ps = ((sub*4 + quad) + l16) & 7;    // row%8 == l16%8 for all tiles
        bf16x8 af[4], bw[4];
#pragma unroll
        for (int mt = 0; mt < 4; ++mt)
          af[mt] = *(const bf16x8*)(As + (wm*64 + mt*16 + l16)*64 + ps*8);
#pragma unroll
        for (int nt = 0; nt < 4; ++nt)
          bw[nt] = *(const bf16x8*)(Bs + (wn*64 + nt*16 + l16)*64 + ps*8);
#pragma unroll
        for (int mt = 0; mt < 4; ++mt)
#pragma unroll
          for (int nt = 0; nt < 4; ++nt)
            acc[mt][nt] = __builtin_amdgcn_mfma_f32_16x16x32_bf16(af[mt], bw[nt], acc[mt][nt], 0, 0, 0);
      }
      __syncthreads();
    }
  }
  // bf16 split-K partial (no atomics)
  unsigned short* hp = hidp + (size_t)kz*NM*NHID;
#pragma unroll
  for (int mt = 0; mt < 4; ++mt) {
    const int m = tileM*128 + wm*64 + mt*16 + quad*4;   // D: row = quad*4+reg
#pragma unroll
    for (int nt = 0; nt < 4; ++nt) {
      const int o = o0 + wn*64 + nt*16 + l16;           // D: col = lane&15
#pragma unroll
      for (int r = 0; r < 4; ++r)
        hp[(size_t)(m + r)*NHID + o] = f2bf(acc[mt][nt][r]);
    }
  }
}

// ---------------- split-K reduce + bias + ReLU -> bf16 hid ----------------
__global__ __launch_bounds__(256) void k_reduce(const unsigned short* __restrict__ hidp,
                                                const float* __restrict__ b1,
                                                unsigned short* __restrict__ hidb, int nsplit) {
  const size_t i8 = ((size_t)blockIdx.x*256 + threadIdx.x) * 8;
  float s[8] = {0.f,0.f,0.f,0.f,0.f,0.f,0.f,0.f};
  for (int sp = 0; sp < nsplit; ++sp) {
    const uint4 v = *(const uint4*)(hidp + (size_t)sp*NM*NHID + i8);
    s[0] += __uint_as_float(v.x << 16); s[1] += __uint_as_float(v.x & 0xffff0000u);
    s[2] += __uint_as_float(v.y << 16); s[3] += __uint_as_float(v.y & 0xffff0000u);
    s[4] += __uint_as_float(v.z << 16); s[5] += __uint_as_float(v.z & 0xffff0000u);
    s[6] += __uint_as_float(v.w << 16); s[7] += __uint_as_float(v.w & 0xffff0000u);
  }
  const int cb0 = (int)(i8 & 511);
  unsigned int p[4];
#pragma unroll
  for (int k = 0; k < 4; ++k) {
    const unsigned int lo = f2bf(fmaxf(s[2*k]   + b1[cb0 + 2*k],     0.f));
    const unsigned int hi = f2bf(fmaxf(s[2*k+1] + b1[cb0 + 2*k + 1], 0.f));
    p[k] = lo | (hi << 16);
  }
  *(uint4*)(hidb + i8) = make_uint4(p[0], p[1], p[2], p[3]);
}

// ---------------- conf+reg heads: GEMM M=4096, N=48, K=512, 64-row tiles ----------------
__global__ __launch_bounds__(256) void k_heads(const unsigned short* __restrict__ hid,
                                               const unsigned short* __restrict__ wh,
                                               const float* __restrict__ hb,
                                               float* __restrict__ heads) {
  __shared__ unsigned short As[64*40] __attribute__((aligned(16)));
  __shared__ unsigned short Bs[48*40] __attribute__((aligned(16)));
  const int t = threadIdx.x, tile = blockIdx.x;     // 64 tiles of 64 rows
  const int wv = t >> 6, lane = t & 63;
  const int quad = lane >> 4, l16 = lane & 15;
  floatx4 acc[3];
#pragma unroll
  for (int nt = 0; nt < 3; ++nt) acc[nt] = (floatx4){0.f, 0.f, 0.f, 0.f};
  const int row0 = t >> 2, seg = t & 3;
  for (int c0 = 0; c0 < 512; c0 += 32) {
    *(uint4*)(As + row0*40 + seg*8) =
        *(const uint4*)(hid + ((size_t)(tile*64 + row0))*512 + c0 + seg*8);
    if (t < 192)
      *(uint4*)(Bs + row0*40 + seg*8) =
          *(const uint4*)(wh + (size_t)row0*512 + c0 + seg*8);
    __syncthreads();
    const bf16x8 af = *(const bf16x8*)(As + (wv*16 + l16)*40 + quad*8);
#pragma unroll
    for (int nt = 0; nt < 3; ++nt) {
      const bf16x8 bw = *(const bf16x8*)(Bs + (nt*16 + l16)*40 + quad*8);
      acc[nt] = __builtin_amdgcn_mfma_f32_16x16x32_bf16(af, bw, acc[nt], 0, 0, 0);
    }
    __syncthreads();
  }
  const int m = tile*64 + wv*16 + quad*4;
#pragma unroll
  for (int nt = 0; nt < 3; ++nt) {
    const int nn = nt*16 + l16;
    const float bv = hb[nn];
#pragma unroll
    for (int r = 0; r < 4; ++r)
      heads[(size_t)(m + r)*48 + nn] = acc[nt][r] + bv;
  }
}

// ---------------- per-GT max IoU over all anchors ----------------
__global__ __launch_bounds__(256) void k_maxg(const float* __restrict__ gtb,
                                              unsigned int* __restrict__ maxg) {
  const int idx = blockIdx.x*256 + threadIdx.x;     // (b,n)
  const int b = idx / NANC, n = idx - b*NANC;
  const Anc A = anc_of(n);
  const int lane = threadIdx.x & 63;
  for (int g = 0; g < NG; ++g) {
    const float4 gp = *(const float4*)(gtb + ((size_t)b*NG + g)*4);
    float m = iou_one(A, gp);
#pragma unroll
    for (int o = 32; o > 0; o >>= 1) m = fmaxf(m, __shfl_xor(m, o));
    if (lane == 0) atomicMax(&maxg[b*NG + g], __float_as_uint(m));  // iou>=0: bits monotone
  }
}

__device__ __forceinline__ float softplusf(float z) {
  return fmaxf(z, 0.f) + log1pf(expf(-fabsf(z)));
}
__device__ __forceinline__ float sl1f(float d) {
  const float ad = fabsf(d);
  return ad < 1.f ? 0.5f*d*d : ad - 0.5f;
}

// ---------------- assignment, losses, proposals, fused finalize ----------------
__global__ __launch_bounds__(256) void k_assign(const unsigned int* __restrict__ maxg,
                                                const float* __restrict__ heads,
                                                const float* __restrict__ gtb,
                                                float* __restrict__ out,
                                                float* __restrict__ sums,
                                                unsigned int* __restrict__ ctr) {
  const int idx = blockIdx.x*256 + threadIdx.x;
  const int b = idx / NANC, n = idx - b*NANC;
  const int a = n % 9, pix = n / 9;
  const Anc A = anc_of(n);

  float mx = -1.f; int gi = 0; bool pos = false;
  for (int g = 0; g < NG; ++g) {
    const float4 gp = *(const float4*)(gtb + ((size_t)b*NG + g)*4);
    const float v = iou_one(A, gp);                  // bit-identical to k_maxg
    const float mg = __uint_as_float(maxg[b*NG + g]);
    pos = pos || (v > 0.7f) || ((v == mg) && (mg > 1e-8f));
    if (v > mx) { mx = v; gi = g; }                  // first-max argmax
  }
  const bool neg = (mx < 0.3f) && !pos;
  const float posf = pos ? 1.f : 0.f;

  const int m = b*1024 + pix;
  const float* hrow = heads + (size_t)m*48;
  const float conf = hrow[a];
  const float of0 = hrow[9 + a*4 + 0];
  const float of1 = hrow[9 + a*4 + 1];
  const float of2 = hrow[9 + a*4 + 2];
  const float of3 = hrow[9 + a*4 + 3];

  float cls = 0.f;
  if (pos) cls = softplusf(-conf);
  else if (neg) cls = softplusf(conf);

  const float acx = (A.x1 + A.x2)*0.5f, acy = (A.y1 + A.y2)*0.5f;
  const float aw = A.x2 - A.x1, ah = A.y2 - A.y1;
  float reg = 0.f;
  if (pos) {
    const float4 gp = *(const float4*)(gtb + ((size_t)b*NG + gi)*4);
    const float gx1 = gp.x*0.03125f, gy1 = gp.y*0.03125f;
    const float gx2 = gp.z*0.03125f, gy2 = gp.w*0.03125f;
    const float gcx = (gx1+gx2)*0.5f, gcy = (gy1+gy2)*0.5f;
    const float gw = gx2-gx1, gh = gy2-gy1;
    const float t0 = (gcx-acx)/(aw+1e-8f), t1 = (gcy-acy)/(ah+1e-8f);
    const float t2 = logf((gw+1e-8f)/(aw+1e-8f)), t3 = logf((gh+1e-8f)/(ah+1e-8f));
    reg = sl1f(of0-t0) + sl1f(of1-t1) + sl1f(of2-t2) + sl1f(of3-t3);
  }

  const float pcx = acx + of0*aw, pcy = acy + of1*ah;
  const float pw = aw*expf(of2), ph = ah*expf(of3);
  float* op = out + 1 + (size_t)idx*4;
  op[0] = (pcx - pw*0.5f)*posf;
  op[1] = (pcy - ph*0.5f)*posf;
  op[2] = (pcx + pw*0.5f)*posf;
  op[3] = (pcy + ph*0.5f)*posf;
  out[1 + 4*(size_t)NB*NANC + idx] = posf;

  float cs = cls, rs = reg;
#pragma unroll
  for (int o = 32; o > 0; o >>= 1) { cs += __shfl_xor(cs, o); rs += __shfl_xor(rs, o); }
  if ((threadIdx.x & 63) == 0) { atomicAdd(&sums[0], cs); atomicAdd(&sums[1], rs); }

  // fused finalize: last block to finish writes the scalar loss
  __syncthreads();
  if (threadIdx.x == 0) {
    __threadfence();
    const unsigned int c = atomicAdd(ctr, 1u);
    if (c == 143u) {                                  // 144 blocks total
      __threadfence();
      const float fcs = atomicAdd(&sums[0], 0.f);     // device-scope read
      const float frs = atomicAdd(&sums[1], 0.f);
      out[0] = fcs*0.25f + 5.f*(frs*0.25f);           // w_conf*cls/B + w_reg*reg/B
    }
  }
}

extern "C" void kernel_launch(void* const* d_in, const int* in_sizes, int n_in,
                              void* d_out, int out_size, void* d_ws, size_t ws_size,
                              hipStream_t stream) {
  const float* x   = (const float*)d_in[0];
  const float* gtb = (const float*)d_in[1];
  // d_in[2] = gt_classes (unused by the loss)
  const float* w1  = (const float*)d_in[3];
  const float* b1  = (const float*)d_in[4];
  const float* cw  = (const float*)d_in[5];
  const float* cb  = (const float*)d_in[6];
  const float* rw  = (const float*)d_in[7];
  const float* rb  = (const float*)d_in[8];
  float* out = (float*)d_out;
  char* ws = (char*)d_ws;

  unsigned short* xh    = (unsigned short*)(ws + OFF_XH);
  unsigned short* wt    = (unsigned short*)(ws + OFF_WT);
  unsigned short* hidb  = (unsigned short*)(ws + OFF_HIDB);
  unsigned short* wh    = (unsigned short*)(ws + OFF_WH);
  float*          hb    = (float*)(ws + OFF_HB);
  float*          heads = (float*)(ws + OFF_HEADS);
  unsigned int*   maxg  = (unsigned int*)(ws + OFF_MAXG);
  float*          sums  = (float*)(ws + OFF_SUMS);
  unsigned int*   ctr   = (unsigned int*)(ws + OFF_CTR);
  unsigned short* hidp  = (unsigned short*)(ws + OFF_HIDP);

  int nsplit = 8;
  while (nsplit > 1 && OFF_HIDP + (size_t)nsplit*NM*NHID*2 > ws_size) nsplit >>= 1;
  const int csplit = NC / nsplit;

  hipMemsetAsync(xh, 0, OFF_WT - OFF_XH, stream);        // zero halo (interior overwritten)
  hipMemsetAsync(ws + OFF_MAXG, 0, 768, stream);         // maxg + sums + ctr

  k_transpose_x<<<dim3(32, 32, 4), 256, 0, stream>>>(x, xh);
  k_prep_w<<<4192, 256, 0, stream>>>(w1, wt, cw, cb, rw, rb, wh, hb);
  k_conv_gemm<<<dim3(32, 4, nsplit), 256, 0, stream>>>(xh, wt, hidp, csplit);
  k_reduce<<<1024, 256, 0, stream>>>(hidp, b1, hidb, nsplit);
  k_heads<<<64, 256, 0, stream>>>(hidb, wh, hb, heads);
  k_maxg<<<144, 256, 0, stream>>>(gtb, maxg);
  k_assign<<<144, 256, 0, stream>>>(maxg, heads, gtb, out, sums, ctr);
}

// Round 4
// 246.400 us; speedup vs baseline: 1.6906x; 1.1678x over previous
//
#include <hip/hip_runtime.h>

// RPN forward on gfx950. Heavy op = 3x3 conv (2048->512) = 77.3 GFLOP -> bf16 MFMA.
// R3: dispatch-count surgery. 9 graph nodes -> 4:
//   k_prep  = x-transpose + w-transpose + head-w prep + halo-ring zero + flag zero
//   k_conv  = unchanged (954 TF, 0 bank conflicts, structural plateau)
//   k_heads = heads GEMM with inline split-K reduce (+bias+ReLU), plus per-GT
//             max-IoU blocks riding in the same dispatch (independent work)
//   k_assign= losses + proposals + fused finalize
// pos/neg assignment in strict IEEE f32 (no contraction) to bit-match numpy ref.

typedef __bf16 bf16x8 __attribute__((ext_vector_type(8)));
typedef float floatx4 __attribute__((ext_vector_type(4)));

#define NB 4
#define NC 2048
#define NH 32
#define NW 32
#define NHID 512
#define NA 9
#define NG 20
#define NANC 9216            // NH*NW*NA
#define NM 4096              // NB*NH*NW

// workspace layout (bytes)
#define OFF_XH    0ull            // [4][34][34][2048] bf16 (zero halo) = 18939904
#define OFF_WT    18939904ull     // [9][512][2048]    bf16 = 18874368
#define OFF_WH    37814272ull     // [48][512]         bf16 =    49152
#define OFF_HB    37863424ull     // [48]              f32  (pad 256)
#define OFF_HEADS 37863680ull     // [4096][48]        f32  =   786432
#define OFF_MAXG  38650112ull     // [4][20] uint bits (pad 512)
#define OFF_SUMS  38650624ull     // [2] f32 (pad 128)
#define OFF_CTR   38650752ull     // [1] uint (pad 128)
#define OFF_HIDP  38650880ull     // [nsplit][4096][512] bf16, 4194304 each

// k_prep block ranges
#define PREP_TX   4096            // x transpose
#define PREP_W    4096            // w transpose
#define PREP_WH   96              // head weights
#define PREP_HALO 528             // 4 b * 132 halo cells
#define PREP_NBLK (PREP_TX + PREP_W + PREP_WH + PREP_HALO + 1)

__device__ __forceinline__ unsigned short f2bf(float f) {
  unsigned int u = __float_as_uint(f);
  u = (u + 0x7fffu + ((u >> 16) & 1u)) >> 16;   // RNE
  return (unsigned short)u;
}

// async global->LDS, 16B/lane; LDS dest = wave-uniform base + lane*16
__device__ __forceinline__ void gload16(const void* g, void* l) {
  __builtin_amdgcn_global_load_lds(
      (const __attribute__((address_space(1))) unsigned int*)g,
      (__attribute__((address_space(3))) unsigned int*)l, 16, 0, 0);
}

// anchor widths/heights: aw = repeat([2,4,6],3); ah = (scale*ratio) flattened
__constant__ float c_aw[9] = {2.f,2.f,2.f,4.f,4.f,4.f,6.f,6.f,6.f};
__constant__ float c_ah[9] = {1.f,2.f,3.f,2.f,4.f,6.f,3.f,6.f,9.f};

// ---- shared strict-f32 anchor/IoU helpers (bit-identical in maxg + assign) ----
struct Anc { float x1, y1, x2, y2, areaA; };
__device__ __forceinline__ Anc anc_of(int n) {
  const int a = n % 9, pix = n / 9;
  const int xi = pix & 31, yi = pix >> 5;
  const float hw = c_aw[a]*0.5f, hh = c_ah[a]*0.5f;
  const float xc = xi + 0.5f, yc = yi + 0.5f;
  Anc A;
  A.x1 = fminf(fmaxf(xc - hw, 0.f), 32.f);
  A.y1 = fminf(fmaxf(yc - hh, 0.f), 32.f);
  A.x2 = fminf(fmaxf(xc + hw, 0.f), 32.f);
  A.y2 = fminf(fmaxf(yc + hh, 0.f), 32.f);
  A.areaA = __fmul_rn(__fsub_rn(A.x2, A.x1), __fsub_rn(A.y2, A.y1));
  return A;
}
__device__ __forceinline__ float iou_one(const Anc& A, float4 gp) {
  const float gx1 = gp.x * 0.03125f, gy1 = gp.y * 0.03125f;   // /32 exact
  const float gx2 = gp.z * 0.03125f, gy2 = gp.w * 0.03125f;
  const float dx = fmaxf(__fsub_rn(fminf(A.x2, gx2), fmaxf(A.x1, gx1)), 0.f);
  const float dy = fmaxf(__fsub_rn(fminf(A.y2, gy2), fmaxf(A.y1, gy1)), 0.f);
  const float inter = __fmul_rn(dx, dy);
  const float areaG = __fmul_rn(__fsub_rn(gx2, gx1), __fsub_rn(gy2, gy1));
  const float den = __fadd_rn(__fsub_rn(__fadd_rn(A.areaA, areaG), inter), 1e-8f);
  return __fdiv_rn(inter, den);
}

// ---------------- fused prep: transposes + halo zero + flag zero ----------------
__global__ __launch_bounds__(256) void k_prep(const float* __restrict__ x,
                                              const float* __restrict__ w1,
                                              const float* __restrict__ cw, const float* __restrict__ cb,
                                              const float* __restrict__ rw, const float* __restrict__ rb,
                                              unsigned short* __restrict__ xh,
                                              unsigned short* __restrict__ wt,
                                              unsigned short* __restrict__ wh, float* __restrict__ hb,
                                              unsigned int* __restrict__ maxg,
                                              float* __restrict__ sums, unsigned int* __restrict__ ctr) {
  const int bid = blockIdx.x;
  const int tid = threadIdx.x;

  if (bid < PREP_TX) {                       // ---- x: NCHW f32 -> halo NHWC bf16
    __shared__ float tile[64][33];
    const int c0 = (bid & 31) << 6;
    const int h  = (bid >> 5) & 31;
    const int b  = bid >> 10;
    const int w = tid & 31, cl = tid >> 5;
    const float* src = x + (((size_t)b*NC + c0)*NH + h)*NW;
#pragma unroll
    for (int j = 0; j < 8; ++j) {
      const int c = cl + j*8;
      tile[c][w] = src[(size_t)c*NH*NW + w];
    }
    __syncthreads();
    unsigned short* dst = xh + ((size_t)(b*34 + h + 1)*34 + 1)*2048 + c0;
    const int c2 = (tid & 31)*2, wr = tid >> 5;
#pragma unroll
    for (int j = 0; j < 4; ++j) {
      const int ww = wr + j*8;
      const unsigned int lo = f2bf(tile[c2][ww]), hi = f2bf(tile[c2+1][ww]);
      *(unsigned int*)(dst + (size_t)ww*2048 + c2) = lo | (hi << 16);
    }
    return;
  }
  if (bid < PREP_TX + PREP_W) {              // ---- w1 -> [g][O][C] bf16
    const int t = (bid - PREP_TX)*256 + tid; // t = o*2048 + c
    const float* src = w1 + (size_t)t * 9;   // 9 contiguous taps
#pragma unroll
    for (int g = 0; g < 9; ++g)
      wt[(size_t)g*NHID*NC + t] = f2bf(src[g]);
    return;
  }
  if (bid < PREP_TX + PREP_W + PREP_WH) {    // ---- head weights [48][512] + bias
    const int t = (bid - PREP_TX - PREP_W)*256 + tid;
    const int n = t >> 9, c = t & 511;
    float v = 0.f;
    if (n < 9) v = cw[n*512 + c];
    else if (n < 45) v = rw[(n-9)*512 + c];
    wh[t] = f2bf(v);
    if (c == 0) {
      float bv = 0.f;
      if (n < 9) bv = cb[n];
      else if (n < 45) bv = rb[n-9];
      hb[n] = bv;
    }
    return;
  }
  if (bid < PREP_TX + PREP_W + PREP_WH + PREP_HALO) {  // ---- zero one halo cell (2048 bf16)
    const int q = bid - (PREP_TX + PREP_W + PREP_WH);
    const int b = q / 132, hc = q - b*132;
    int hh, ww;
    if (hc < 34)       { hh = 0;        ww = hc; }
    else if (hc < 68)  { hh = 33;       ww = hc - 34; }
    else if (hc < 100) { hh = hc - 67;  ww = 0; }      // 1..32
    else               { hh = hc - 99;  ww = 33; }     // 1..32
    uint4* dst = (uint4*)(xh + ((size_t)((b*34 + hh)*34 + ww))*2048);
    dst[tid] = make_uint4(0u, 0u, 0u, 0u);             // 256*16B = 4096B = 2048 bf16
    return;
  }
  // ---- flags
  if (tid < 80) maxg[tid] = 0u;
  else if (tid < 82) sums[tid - 80] = 0.f;
  else if (tid == 82) *ctr = 0u;
}

// ---------------- conv 3x3 as implicit GEMM, bf16 MFMA ----------------
// M=4096, N=512, K=9*2048. Tile 128x128, BK=64 (32 MFMA per barrier). Grid (32,4,nsplit).
// global_load_lds 16B/lane; seg swizzle pos=(s+row)&7 -> conflict-free b128 reads (measured 0).
__global__ __launch_bounds__(256, 4) void k_conv_gemm(const unsigned short* __restrict__ xh,
                                                      const unsigned short* __restrict__ wt,
                                                      unsigned short* __restrict__ hidp, int csplit) {
  __shared__ unsigned short As[128*64] __attribute__((aligned(16)));   // 16 KB
  __shared__ unsigned short Bs[128*64] __attribute__((aligned(16)));   // 16 KB
  const int t = threadIdx.x;
  const int tileM = blockIdx.x, tileN = blockIdx.y, kz = blockIdx.z;
  const int b = tileM >> 3, h0 = (tileM & 7) << 2;
  const int o0 = tileN << 7;
  const int wv = t >> 6, lane = t & 63;
  const int wm = wv >> 1, wn = wv & 1;
  const int quad = lane >> 4, l16 = lane & 15;
  const int c_base = kz * csplit;

  floatx4 acc[4][4];
#pragma unroll
  for (int mt = 0; mt < 4; ++mt)
#pragma unroll
    for (int nt = 0; nt < 4; ++nt)
      acc[mt][nt] = (floatx4){0.f, 0.f, 0.f, 0.f};

  const int lr = lane >> 3, pos = lane & 7;
  int gA[4], gB[4];
#pragma unroll
  for (int j = 0; j < 4; ++j) {
    const int row = wv*32 + j*8 + lr;
    const int sd = (pos - row) & 7;
    const int hh = h0 + (row >> 5) + 1, ww = (row & 31) + 1;
    gA[j] = ((b*34 + hh)*34 + ww)*2048 + c_base + sd*8;
    gB[j] = (o0 + row)*2048 + c_base + sd*8;
  }

  for (int g = 0; g < 9; ++g) {
    const int dsp = ((g/3 - 1)*34 + (g%3 - 1)) * 2048;
    const unsigned short* wgp = wt + (size_t)g*NHID*NC;
    for (int c0 = 0; c0 < csplit; c0 += 64) {
#pragma unroll
      for (int j = 0; j < 4; ++j) {
        gload16(xh + gA[j] + dsp + c0, As + (wv*32 + j*8)*64);
        gload16(wgp + gB[j] + c0,      Bs + (wv*32 + j*8)*64);
      }
      __syncthreads();
#pragma unroll
      for (int sub = 0; sub < 2; ++sub) {
        const int ps = ((sub*4 + quad) + l16) & 7;
        bf16x8 af[4], bw[4];
#pragma unroll
        for (int mt = 0; mt < 4; ++mt)
          af[mt] = *(const bf16x8*)(As + (wm*64 + mt*16 + l16)*64 + ps*8);
#pragma unroll
        for (int nt = 0; nt < 4; ++nt)
          bw[nt] = *(const bf16x8*)(Bs + (wn*64 + nt*16 + l16)*64 + ps*8);
#pragma unroll
        for (int mt = 0; mt < 4; ++mt)
#pragma unroll
          for (int nt = 0; nt < 4; ++nt)
            acc[mt][nt] = __builtin_amdgcn_mfma_f32_16x16x32_bf16(af[mt], bw[nt], acc[mt][nt], 0, 0, 0);
      }
      __syncthreads();
    }
  }
  unsigned short* hp = hidp + (size_t)kz*NM*NHID;
#pragma unroll
  for (int mt = 0; mt < 4; ++mt) {
    const int m = tileM*128 + wm*64 + mt*16 + quad*4;   // D: row = quad*4+reg
#pragma unroll
    for (int nt = 0; nt < 4; ++nt) {
      const int o = o0 + wn*64 + nt*16 + l16;           // D: col = lane&15
#pragma unroll
      for (int r = 0; r < 4; ++r)
        hp[(size_t)(m + r)*NHID + o] = f2bf(acc[mt][nt][r]);
    }
  }
}

// ---------------- heads GEMM w/ inline split-K reduce, + per-GT max blocks ----------------
// bid<64: heads tile (M=64 rows, N=48, K=512). bid in [64,144): max-IoU for (b,g) pair.
__global__ __launch_bounds__(256) void k_heads_fused(const unsigned short* __restrict__ hidp,
                                                     const float* __restrict__ b1,
                                                     const unsigned short* __restrict__ wh,
                                                     const float* __restrict__ hb,
                                                     const float* __restrict__ gtb,
                                                     float* __restrict__ heads,
                                                     unsigned int* __restrict__ maxg,
                                                     int nsplit) {
  const int t = threadIdx.x;
  const int bid = blockIdx.x;
  if (bid >= 64) {                    // ---- max IoU over all anchors for one (b,g)
    __shared__ float red[4];
    const int p = bid - 64, b = p / NG, g = p - b*NG;
    const float4 gp = *(const float4*)(gtb + ((size_t)b*NG + g)*4);
    float m = 0.f;                     // iou >= 0
#pragma unroll
    for (int j = 0; j < 36; ++j) {     // 9216 anchors / 256 threads
      const Anc A = anc_of(t + j*256);
      m = fmaxf(m, iou_one(A, gp));
    }
#pragma unroll
    for (int o = 32; o > 0; o >>= 1) m = fmaxf(m, __shfl_xor(m, o));
    if ((t & 63) == 0) red[t >> 6] = m;
    __syncthreads();
    if (t == 0) {
      m = fmaxf(fmaxf(red[0], red[1]), fmaxf(red[2], red[3]));
      maxg[b*NG + g] = __float_as_uint(m);
    }
    return;
  }
  // ---- heads tile
  __shared__ unsigned short As[64*40] __attribute__((aligned(16)));
  __shared__ unsigned short Bs[48*40] __attribute__((aligned(16)));
  const int tile = bid;
  const int wv = t >> 6, lane = t & 63;
  const int quad = lane >> 4, l16 = lane & 15;
  floatx4 acc[3];
#pragma unroll
  for (int nt = 0; nt < 3; ++nt) acc[nt] = (floatx4){0.f, 0.f, 0.f, 0.f};
  const int row0 = t >> 2, seg = t & 3;
  for (int c0 = 0; c0 < 512; c0 += 32) {
    {   // split-K reduce + bias + ReLU -> As (bf16)
      const size_t gi = ((size_t)(tile*64 + row0))*512 + c0 + seg*8;
      float s[8] = {0.f,0.f,0.f,0.f,0.f,0.f,0.f,0.f};
      for (int sp = 0; sp < nsplit; ++sp) {
        const uint4 v = *(const uint4*)(hidp + (size_t)sp*NM*NHID + gi);
        s[0] += __uint_as_float(v.x << 16); s[1] += __uint_as_float(v.x & 0xffff0000u);
        s[2] += __uint_as_float(v.y << 16); s[3] += __uint_as_float(v.y & 0xffff0000u);
        s[4] += __uint_as_float(v.z << 16); s[5] += __uint_as_float(v.z & 0xffff0000u);
        s[6] += __uint_as_float(v.w << 16); s[7] += __uint_as_float(v.w & 0xffff0000u);
      }
      const int cb0 = c0 + seg*8;
      unsigned int pk[4];
#pragma unroll
      for (int k = 0; k < 4; ++k) {
        const unsigned int lo = f2bf(fmaxf(s[2*k]   + b1[cb0 + 2*k],     0.f));
        const unsigned int hi = f2bf(fmaxf(s[2*k+1] + b1[cb0 + 2*k + 1], 0.f));
        pk[k] = lo | (hi << 16);
      }
      *(uint4*)(As + row0*40 + seg*8) = make_uint4(pk[0], pk[1], pk[2], pk[3]);
    }
    if (t < 192)
      *(uint4*)(Bs + row0*40 + seg*8) =
          *(const uint4*)(wh + (size_t)row0*512 + c0 + seg*8);
    __syncthreads();
    const bf16x8 af = *(const bf16x8*)(As + (wv*16 + l16)*40 + quad*8);
#pragma unroll
    for (int nt = 0; nt < 3; ++nt) {
      const bf16x8 bw = *(const bf16x8*)(Bs + (nt*16 + l16)*40 + quad*8);
      acc[nt] = __builtin_amdgcn_mfma_f32_16x16x32_bf16(af, bw, acc[nt], 0, 0, 0);
    }
    __syncthreads();
  }
  const int m = tile*64 + wv*16 + quad*4;
#pragma unroll
  for (int nt = 0; nt < 3; ++nt) {
    const int nn = nt*16 + l16;
    const float bv = hb[nn];
#pragma unroll
    for (int r = 0; r < 4; ++r)
      heads[(size_t)(m + r)*48 + nn] = acc[nt][r] + bv;
  }
}

__device__ __forceinline__ float softplusf(float z) {
  return fmaxf(z, 0.f) + log1pf(expf(-fabsf(z)));
}
__device__ __forceinline__ float sl1f(float d) {
  const float ad = fabsf(d);
  return ad < 1.f ? 0.5f*d*d : ad - 0.5f;
}

// ---------------- assignment, losses, proposals, fused finalize ----------------
__global__ __launch_bounds__(256) void k_assign(const unsigned int* __restrict__ maxg,
                                                const float* __restrict__ heads,
                                                const float* __restrict__ gtb,
                                                float* __restrict__ out,
                                                float* __restrict__ sums,
                                                unsigned int* __restrict__ ctr) {
  const int idx = blockIdx.x*256 + threadIdx.x;
  const int b = idx / NANC, n = idx - b*NANC;
  const int a = n % 9, pix = n / 9;
  const Anc A = anc_of(n);

  float mx = -1.f; int gi = 0; bool pos = false;
  for (int g = 0; g < NG; ++g) {
    const float4 gp = *(const float4*)(gtb + ((size_t)b*NG + g)*4);
    const float v = iou_one(A, gp);                  // bit-identical to maxg path
    const float mg = __uint_as_float(maxg[b*NG + g]);
    pos = pos || (v > 0.7f) || ((v == mg) && (mg > 1e-8f));
    if (v > mx) { mx = v; gi = g; }                  // first-max argmax
  }
  const bool neg = (mx < 0.3f) && !pos;
  const float posf = pos ? 1.f : 0.f;

  const int m = b*1024 + pix;
  const float* hrow = heads + (size_t)m*48;
  const float conf = hrow[a];
  const float of0 = hrow[9 + a*4 + 0];
  const float of1 = hrow[9 + a*4 + 1];
  const float of2 = hrow[9 + a*4 + 2];
  const float of3 = hrow[9 + a*4 + 3];

  float cls = 0.f;
  if (pos) cls = softplusf(-conf);
  else if (neg) cls = softplusf(conf);

  const float acx = (A.x1 + A.x2)*0.5f, acy = (A.y1 + A.y2)*0.5f;
  const float aw = A.x2 - A.x1, ah = A.y2 - A.y1;
  float reg = 0.f;
  if (pos) {
    const float4 gp = *(const float4*)(gtb + ((size_t)b*NG + gi)*4);
    const float gx1 = gp.x*0.03125f, gy1 = gp.y*0.03125f;
    const float gx2 = gp.z*0.03125f, gy2 = gp.w*0.03125f;
    const float gcx = (gx1+gx2)*0.5f, gcy = (gy1+gy2)*0.5f;
    const float gw = gx2-gx1, gh = gy2-gy1;
    const float t0 = (gcx-acx)/(aw+1e-8f), t1 = (gcy-acy)/(ah+1e-8f);
    const float t2 = logf((gw+1e-8f)/(aw+1e-8f)), t3 = logf((gh+1e-8f)/(ah+1e-8f));
    reg = sl1f(of0-t0) + sl1f(of1-t1) + sl1f(of2-t2) + sl1f(of3-t3);
  }

  const float pcx = acx + of0*aw, pcy = acy + of1*ah;
  const float pw = aw*expf(of2), ph = ah*expf(of3);
  float* op = out + 1 + (size_t)idx*4;
  op[0] = (pcx - pw*0.5f)*posf;
  op[1] = (pcy - ph*0.5f)*posf;
  op[2] = (pcx + pw*0.5f)*posf;
  op[3] = (pcy + ph*0.5f)*posf;
  out[1 + 4*(size_t)NB*NANC + idx] = posf;

  float cs = cls, rs = reg;
#pragma unroll
  for (int o = 32; o > 0; o >>= 1) { cs += __shfl_xor(cs, o); rs += __shfl_xor(rs, o); }
  if ((threadIdx.x & 63) == 0) { atomicAdd(&sums[0], cs); atomicAdd(&sums[1], rs); }

  // fused finalize: last block to finish writes the scalar loss
  __syncthreads();
  if (threadIdx.x == 0) {
    __threadfence();
    const unsigned int c = atomicAdd(ctr, 1u);
    if (c == 143u) {                                  // 144 blocks total
      __threadfence();
      const float fcs = atomicAdd(&sums[0], 0.f);     // device-scope read
      const float frs = atomicAdd(&sums[1], 0.f);
      out[0] = fcs*0.25f + 5.f*(frs*0.25f);           // w_conf*cls/B + w_reg*reg/B
    }
  }
}

extern "C" void kernel_launch(void* const* d_in, const int* in_sizes, int n_in,
                              void* d_out, int out_size, void* d_ws, size_t ws_size,
                              hipStream_t stream) {
  const float* x   = (const float*)d_in[0];
  const float* gtb = (const float*)d_in[1];
  // d_in[2] = gt_classes (unused by the loss)
  const float* w1  = (const float*)d_in[3];
  const float* b1  = (const float*)d_in[4];
  const float* cw  = (const float*)d_in[5];
  const float* cb  = (const float*)d_in[6];
  const float* rw  = (const float*)d_in[7];
  const float* rb  = (const float*)d_in[8];
  float* out = (float*)d_out;
  char* ws = (char*)d_ws;

  unsigned short* xh    = (unsigned short*)(ws + OFF_XH);
  unsigned short* wt    = (unsigned short*)(ws + OFF_WT);
  unsigned short* wh    = (unsigned short*)(ws + OFF_WH);
  float*          hb    = (float*)(ws + OFF_HB);
  float*          heads = (float*)(ws + OFF_HEADS);
  unsigned int*   maxg  = (unsigned int*)(ws + OFF_MAXG);
  float*          sums  = (float*)(ws + OFF_SUMS);
  unsigned int*   ctr   = (unsigned int*)(ws + OFF_CTR);
  unsigned short* hidp  = (unsigned short*)(ws + OFF_HIDP);

  int nsplit = 8;
  while (nsplit > 1 && OFF_HIDP + (size_t)nsplit*NM*NHID*2 > ws_size) nsplit >>= 1;
  const int csplit = NC / nsplit;

  k_prep<<<PREP_NBLK, 256, 0, stream>>>(x, w1, cw, cb, rw, rb, xh, wt, wh, hb, maxg, sums, ctr);
  k_conv_gemm<<<dim3(32, 4, nsplit), 256, 0, stream>>>(xh, wt, hidp, csplit);
  k_heads_fused<<<144, 256, 0, stream>>>(hidp, b1, wh, hb, gtb, heads, maxg, nsplit);
  k_assign<<<144, 256, 0, stream>>>(maxg, heads, gtb, out, sums, ctr);
}

// Round 5
// 246.041 us; speedup vs baseline: 1.6931x; 1.0015x over previous
//
#include <hip/hip_runtime.h>

// RPN forward on gfx950. Heavy op = 3x3 conv (2048->512) = 77.3 GFLOP -> bf16 MFMA.
// R4: 3 graph nodes. k_prep(+maxg), k_conv(XCD-swizzled), k_heads_assign(fused epilogue).
// pos/neg assignment in strict IEEE f32 (no contraction) to bit-match numpy ref.

typedef __bf16 bf16x8 __attribute__((ext_vector_type(8)));
typedef float floatx4 __attribute__((ext_vector_type(4)));

#define NB 4
#define NC 2048
#define NH 32
#define NW 32
#define NHID 512
#define NA 9
#define NG 20
#define NANC 9216            // NH*NW*NA
#define NM 4096              // NB*NH*NW

// workspace layout (bytes)
#define OFF_XH    0ull            // [4][34][34][2048] bf16 (zero halo) = 18939904
#define OFF_WT    18939904ull     // [9][512][2048]    bf16 = 18874368
#define OFF_WH    37814272ull     // [48][512]         bf16 =    49152
#define OFF_HB    37863424ull     // [48]              f32  (pad 256)
#define OFF_MAXG  37863680ull     // [4][20] uint bits (pad 512)
#define OFF_SUMS  37864192ull     // [2] f32 (pad 128)
#define OFF_CTR   37864320ull     // [1] uint (pad 128)
#define OFF_HIDP  37864448ull     // [nsplit][4096][512] bf16, 4194304 each

// k_prep block ranges
#define PREP_TX   4096
#define PREP_W    4096
#define PREP_WH   96
#define PREP_HALO 528
#define PREP_MAXG 80
#define PREP_NBLK (PREP_TX + PREP_W + PREP_WH + PREP_HALO + PREP_MAXG + 1)

__device__ __forceinline__ unsigned short f2bf(float f) {
  unsigned int u = __float_as_uint(f);
  u = (u + 0x7fffu + ((u >> 16) & 1u)) >> 16;   // RNE
  return (unsigned short)u;
}

// async global->LDS, 16B/lane; LDS dest = wave-uniform base + lane*16
__device__ __forceinline__ void gload16(const void* g, void* l) {
  __builtin_amdgcn_global_load_lds(
      (const __attribute__((address_space(1))) unsigned int*)g,
      (__attribute__((address_space(3))) unsigned int*)l, 16, 0, 0);
}

__constant__ float c_aw[9] = {2.f,2.f,2.f,4.f,4.f,4.f,6.f,6.f,6.f};
__constant__ float c_ah[9] = {1.f,2.f,3.f,2.f,4.f,6.f,3.f,6.f,9.f};

// ---- shared strict-f32 anchor/IoU helpers (bit-identical in prep-maxg + assign) ----
struct Anc { float x1, y1, x2, y2, areaA; };
__device__ __forceinline__ Anc anc_of(int n) {
  const int a = n % 9, pix = n / 9;
  const int xi = pix & 31, yi = pix >> 5;
  const float hw = c_aw[a]*0.5f, hh = c_ah[a]*0.5f;
  const float xc = xi + 0.5f, yc = yi + 0.5f;
  Anc A;
  A.x1 = fminf(fmaxf(xc - hw, 0.f), 32.f);
  A.y1 = fminf(fmaxf(yc - hh, 0.f), 32.f);
  A.x2 = fminf(fmaxf(xc + hw, 0.f), 32.f);
  A.y2 = fminf(fmaxf(yc + hh, 0.f), 32.f);
  A.areaA = __fmul_rn(__fsub_rn(A.x2, A.x1), __fsub_rn(A.y2, A.y1));
  return A;
}
__device__ __forceinline__ float iou_one(const Anc& A, float4 gp) {
  const float gx1 = gp.x * 0.03125f, gy1 = gp.y * 0.03125f;   // /32 exact
  const float gx2 = gp.z * 0.03125f, gy2 = gp.w * 0.03125f;
  const float dx = fmaxf(__fsub_rn(fminf(A.x2, gx2), fmaxf(A.x1, gx1)), 0.f);
  const float dy = fmaxf(__fsub_rn(fminf(A.y2, gy2), fmaxf(A.y1, gy1)), 0.f);
  const float inter = __fmul_rn(dx, dy);
  const float areaG = __fmul_rn(__fsub_rn(gx2, gx1), __fsub_rn(gy2, gy1));
  const float den = __fadd_rn(__fsub_rn(__fadd_rn(A.areaA, areaG), inter), 1e-8f);
  return __fdiv_rn(inter, den);
}

// ---------------- fused prep: transposes + halo zero + per-GT max + flags ----------------
__global__ __launch_bounds__(256) void k_prep(const float* __restrict__ x,
                                              const float* __restrict__ w1,
                                              const float* __restrict__ cw, const float* __restrict__ cb,
                                              const float* __restrict__ rw, const float* __restrict__ rb,
                                              const float* __restrict__ gtb,
                                              unsigned short* __restrict__ xh,
                                              unsigned short* __restrict__ wt,
                                              unsigned short* __restrict__ wh, float* __restrict__ hb,
                                              unsigned int* __restrict__ maxg,
                                              float* __restrict__ sums, unsigned int* __restrict__ ctr) {
  __shared__ float tile[64][33];
  __shared__ float red[4];
  const int bid = blockIdx.x;
  const int tid = threadIdx.x;

  if (bid < PREP_TX) {                       // ---- x: NCHW f32 -> halo NHWC bf16
    const int c0 = (bid & 31) << 6;
    const int h  = (bid >> 5) & 31;
    const int b  = bid >> 10;
    const int w = tid & 31, cl = tid >> 5;
    const float* src = x + (((size_t)b*NC + c0)*NH + h)*NW;
#pragma unroll
    for (int j = 0; j < 8; ++j) {
      const int c = cl + j*8;
      tile[c][w] = src[(size_t)c*NH*NW + w];
    }
    __syncthreads();
    unsigned short* dst = xh + ((size_t)(b*34 + h + 1)*34 + 1)*2048 + c0;
    const int w2 = tid >> 3, c8 = (tid & 7) << 3;   // 16B store per lane
    unsigned int pk[4];
#pragma unroll
    for (int k = 0; k < 4; ++k) {
      const unsigned int lo = f2bf(tile[c8 + 2*k][w2]);
      const unsigned int hi = f2bf(tile[c8 + 2*k + 1][w2]);
      pk[k] = lo | (hi << 16);
    }
    *(uint4*)(dst + (size_t)w2*2048 + c8) = make_uint4(pk[0], pk[1], pk[2], pk[3]);
    return;
  }
  if (bid < PREP_TX + PREP_W) {              // ---- w1 -> [g][O][C] bf16
    const int t = (bid - PREP_TX)*256 + tid; // t = o*2048 + c
    const float* src = w1 + (size_t)t * 9;   // 9 contiguous taps
#pragma unroll
    for (int g = 0; g < 9; ++g)
      wt[(size_t)g*NHID*NC + t] = f2bf(src[g]);
    return;
  }
  if (bid < PREP_TX + PREP_W + PREP_WH) {    // ---- head weights [48][512] + bias
    const int t = (bid - PREP_TX - PREP_W)*256 + tid;
    const int n = t >> 9, c = t & 511;
    float v = 0.f;
    if (n < 9) v = cw[n*512 + c];
    else if (n < 45) v = rw[(n-9)*512 + c];
    wh[t] = f2bf(v);
    if (c == 0) {
      float bv = 0.f;
      if (n < 9) bv = cb[n];
      else if (n < 45) bv = rb[n-9];
      hb[n] = bv;
    }
    return;
  }
  if (bid < PREP_TX + PREP_W + PREP_WH + PREP_HALO) {  // ---- zero one halo cell
    const int q = bid - (PREP_TX + PREP_W + PREP_WH);
    const int b = q / 132, hc = q - b*132;
    int hh, ww;
    if (hc < 34)       { hh = 0;        ww = hc; }
    else if (hc < 68)  { hh = 33;       ww = hc - 34; }
    else if (hc < 100) { hh = hc - 67;  ww = 0; }
    else               { hh = hc - 99;  ww = 33; }
    uint4* dst = (uint4*)(xh + ((size_t)((b*34 + hh)*34 + ww))*2048);
    dst[tid] = make_uint4(0u, 0u, 0u, 0u);
    return;
  }
  if (bid < PREP_TX + PREP_W + PREP_WH + PREP_HALO + PREP_MAXG) {  // ---- maxg (b,g)
    const int p = bid - (PREP_TX + PREP_W + PREP_WH + PREP_HALO);
    const int b = p / NG, g = p - b*NG;
    const float4 gp = *(const float4*)(gtb + ((size_t)b*NG + g)*4);
    float m = 0.f;                     // iou >= 0
#pragma unroll
    for (int j = 0; j < 36; ++j)
      m = fmaxf(m, iou_one(anc_of(tid + j*256), gp));
#pragma unroll
    for (int o = 32; o > 0; o >>= 1) m = fmaxf(m, __shfl_xor(m, o));
    if ((tid & 63) == 0) red[tid >> 6] = m;
    __syncthreads();
    if (tid == 0)
      maxg[b*NG + g] = __float_as_uint(fmaxf(fmaxf(red[0], red[1]), fmaxf(red[2], red[3])));
    return;
  }
  if (tid < 2) sums[tid] = 0.f;
  else if (tid == 2) *ctr = 0u;
}

// ---------------- conv 3x3 as implicit GEMM, bf16 MFMA, XCD-swizzled ----------------
// M=4096, N=512, K=9*2048. Tile 128x128, BK=64. 1-D grid; kz = L & (nsplit-1) so all
// blocks sharing a kz c-slice hit the same XCD (round-robin heuristic): the 4.7 MB
// (xh+wt) c-slice lives in that XCD's L2.
__global__ __launch_bounds__(256, 4) void k_conv_gemm(const unsigned short* __restrict__ xh,
                                                      const unsigned short* __restrict__ wt,
                                                      unsigned short* __restrict__ hidp,
                                                      int csplit, int ksh) {
  __shared__ unsigned short As[128*64] __attribute__((aligned(16)));   // 16 KB
  __shared__ unsigned short Bs[128*64] __attribute__((aligned(16)));   // 16 KB
  const int t = threadIdx.x;
  const int L = blockIdx.x;
  const int kz = L & ((1 << ksh) - 1);
  const int rem = L >> ksh;
  const int tileM = rem & 31, tileN = rem >> 5;
  const int b = tileM >> 3, h0 = (tileM & 7) << 2;
  const int o0 = tileN << 7;
  const int wv = t >> 6, lane = t & 63;
  const int wm = wv >> 1, wn = wv & 1;
  const int quad = lane >> 4, l16 = lane & 15;
  const int c_base = kz * csplit;

  floatx4 acc[4][4];
#pragma unroll
  for (int mt = 0; mt < 4; ++mt)
#pragma unroll
    for (int nt = 0; nt < 4; ++nt)
      acc[mt][nt] = (floatx4){0.f, 0.f, 0.f, 0.f};

  const int lr = lane >> 3, pos = lane & 7;
  int gA[4], gB[4];
#pragma unroll
  for (int j = 0; j < 4; ++j) {
    const int row = wv*32 + j*8 + lr;
    const int sd = (pos - row) & 7;                   // seg swizzle (0 conflicts, measured)
    const int hh = h0 + (row >> 5) + 1, ww = (row & 31) + 1;
    gA[j] = ((b*34 + hh)*34 + ww)*2048 + c_base + sd*8;
    gB[j] = (o0 + row)*2048 + c_base + sd*8;
  }

  for (int g = 0; g < 9; ++g) {
    const int dsp = ((g/3 - 1)*34 + (g%3 - 1)) * 2048;
    const unsigned short* wgp = wt + (size_t)g*NHID*NC;
    for (int c0 = 0; c0 < csplit; c0 += 64) {
#pragma unroll
      for (int j = 0; j < 4; ++j) {
        gload16(xh + gA[j] + dsp + c0, As + (wv*32 + j*8)*64);
        gload16(wgp + gB[j] + c0,      Bs + (wv*32 + j*8)*64);
      }
      __syncthreads();
#pragma unroll
      for (int sub = 0; sub < 2; ++sub) {
        const int ps = ((sub*4 + quad) + l16) & 7;
        bf16x8 af[4], bw[4];
#pragma unroll
        for (int mt = 0; mt < 4; ++mt)
          af[mt] = *(const bf16x8*)(As + (wm*64 + mt*16 + l16)*64 + ps*8);
#pragma unroll
        for (int nt = 0; nt < 4; ++nt)
          bw[nt] = *(const bf16x8*)(Bs + (wn*64 + nt*16 + l16)*64 + ps*8);
#pragma unroll
        for (int mt = 0; mt < 4; ++mt)
#pragma unroll
          for (int nt = 0; nt < 4; ++nt)
            acc[mt][nt] = __builtin_amdgcn_mfma_f32_16x16x32_bf16(af[mt], bw[nt], acc[mt][nt], 0, 0, 0);
      }
      __syncthreads();
    }
  }
  unsigned short* hp = hidp + (size_t)kz*NM*NHID;
#pragma unroll
  for (int mt = 0; mt < 4; ++mt) {
    const int m = tileM*128 + wm*64 + mt*16 + quad*4;   // D: row = quad*4+reg
#pragma unroll
    for (int nt = 0; nt < 4; ++nt) {
      const int o = o0 + wn*64 + nt*16 + l16;           // D: col = lane&15
#pragma unroll
      for (int r = 0; r < 4; ++r)
        hp[(size_t)(m + r)*NHID + o] = f2bf(acc[mt][nt][r]);
    }
  }
}

__device__ __forceinline__ float softplusf(float z) {
  return fmaxf(z, 0.f) + log1pf(expf(-fabsf(z)));
}
__device__ __forceinline__ float sl1f(float d) {
  const float ad = fabsf(d);
  return ad < 1.f ? 0.5f*d*d : ad - 0.5f;
}

// ---------------- heads GEMM (inline split-K reduce) + fused assignment ----------------
// 64 blocks; block = 64 pixels of one batch. GEMM M=64,N=48,K=512 -> LDS; then the same
// block does assignment/losses/proposals for its 576 anchors. Last block finalizes loss.
__global__ __launch_bounds__(256) void k_heads_assign(const unsigned short* __restrict__ hidp,
                                                      const float* __restrict__ b1,
                                                      const unsigned short* __restrict__ wh,
                                                      const float* __restrict__ hb,
                                                      const float* __restrict__ gtb,
                                                      const unsigned int* __restrict__ maxg,
                                                      float* __restrict__ out,
                                                      float* __restrict__ sums,
                                                      unsigned int* __restrict__ ctr,
                                                      int nsplit) {
  __shared__ unsigned short As[64*40] __attribute__((aligned(16)));
  __shared__ unsigned short Bs[48*40] __attribute__((aligned(16)));
  __shared__ float hl[64][49];
  __shared__ float4 gt_s[20];
  __shared__ float  mg_s[20];
  const int t = threadIdx.x;
  const int tile = blockIdx.x;
  const int b = tile >> 4, pix0 = (tile & 15) << 6;

  if (t < 20) {
    gt_s[t] = *(const float4*)(gtb + ((size_t)b*NG + t)*4);
    mg_s[t] = __uint_as_float(maxg[b*NG + t]);
  }

  const int wv = t >> 6, lane = t & 63;
  const int quad = lane >> 4, l16 = lane & 15;
  floatx4 acc[3];
#pragma unroll
  for (int nt = 0; nt < 3; ++nt) acc[nt] = (floatx4){0.f, 0.f, 0.f, 0.f};
  const int row0 = t >> 2, seg = t & 3;
  for (int c0 = 0; c0 < 512; c0 += 32) {
    {   // split-K reduce + bias + ReLU -> As (bf16)
      const size_t gi = ((size_t)(tile*64 + row0))*512 + c0 + seg*8;
      float s[8] = {0.f,0.f,0.f,0.f,0.f,0.f,0.f,0.f};
      for (int sp = 0; sp < nsplit; ++sp) {
        const uint4 v = *(const uint4*)(hidp + (size_t)sp*NM*NHID + gi);
        s[0] += __uint_as_float(v.x << 16); s[1] += __uint_as_float(v.x & 0xffff0000u);
        s[2] += __uint_as_float(v.y << 16); s[3] += __uint_as_float(v.y & 0xffff0000u);
        s[4] += __uint_as_float(v.z << 16); s[5] += __uint_as_float(v.z & 0xffff0000u);
        s[6] += __uint_as_float(v.w << 16); s[7] += __uint_as_float(v.w & 0xffff0000u);
      }
      const int cb0 = c0 + seg*8;
      unsigned int pk[4];
#pragma unroll
      for (int k = 0; k < 4; ++k) {
        const unsigned int lo = f2bf(fmaxf(s[2*k]   + b1[cb0 + 2*k],     0.f));
        const unsigned int hi = f2bf(fmaxf(s[2*k+1] + b1[cb0 + 2*k + 1], 0.f));
        pk[k] = lo | (hi << 16);
      }
      *(uint4*)(As + row0*40 + seg*8) = make_uint4(pk[0], pk[1], pk[2], pk[3]);
    }
    if (t < 192)
      *(uint4*)(Bs + row0*40 + seg*8) =
          *(const uint4*)(wh + (size_t)row0*512 + c0 + seg*8);
    __syncthreads();
    const bf16x8 af = *(const bf16x8*)(As + (wv*16 + l16)*40 + quad*8);
#pragma unroll
    for (int nt = 0; nt < 3; ++nt) {
      const bf16x8 bw = *(const bf16x8*)(Bs + (nt*16 + l16)*40 + quad*8);
      acc[nt] = __builtin_amdgcn_mfma_f32_16x16x32_bf16(af, bw, acc[nt], 0, 0, 0);
    }
    __syncthreads();
  }
  // epilogue -> LDS (row = wv*16 + quad*4 + r, col = nt*16 + l16)
#pragma unroll
  for (int nt = 0; nt < 3; ++nt) {
    const int nn = nt*16 + l16;
    const float bv = hb[nn];
#pragma unroll
    for (int r = 0; r < 4; ++r)
      hl[wv*16 + quad*4 + r][nn] = acc[nt][r] + bv;
  }
  __syncthreads();

  // ---- assignment, losses, proposals for this block's 576 anchors ----
  float cs = 0.f, rs = 0.f;
#pragma unroll
  for (int k = 0; k < 3; ++k) {
    const int q = t + k*256;
    if (q < 576) {
      const int pixL = q / 9, a = q - pixL*9;
      const int pix = pix0 + pixL;
      const int n = pix*9 + a;
      const int idx = b*NANC + n;
      const Anc A = anc_of(n);

      float mx = -1.f; int gi = 0; bool pos = false;
      for (int g = 0; g < NG; ++g) {
        const float v = iou_one(A, gt_s[g]);         // bit-identical to prep-maxg
        const float mg = mg_s[g];
        pos = pos || (v > 0.7f) || ((v == mg) && (mg > 1e-8f));
        if (v > mx) { mx = v; gi = g; }              // first-max argmax
      }
      const bool neg = (mx < 0.3f) && !pos;
      const float posf = pos ? 1.f : 0.f;

      const float conf = hl[pixL][a];
      const float of0 = hl[pixL][9 + a*4 + 0];
      const float of1 = hl[pixL][9 + a*4 + 1];
      const float of2 = hl[pixL][9 + a*4 + 2];
      const float of3 = hl[pixL][9 + a*4 + 3];

      if (pos) cs += softplusf(-conf);
      else if (neg) cs += softplusf(conf);

      const float acx = (A.x1 + A.x2)*0.5f, acy = (A.y1 + A.y2)*0.5f;
      const float aw = A.x2 - A.x1, ah = A.y2 - A.y1;
      if (pos) {
        const float4 gp = gt_s[gi];
        const float gx1 = gp.x*0.03125f, gy1 = gp.y*0.03125f;
        const float gx2 = gp.z*0.03125f, gy2 = gp.w*0.03125f;
        const float gcx = (gx1+gx2)*0.5f, gcy = (gy1+gy2)*0.5f;
        const float gw = gx2-gx1, gh = gy2-gy1;
        const float t0 = (gcx-acx)/(aw+1e-8f), t1 = (gcy-acy)/(ah+1e-8f);
        const float t2 = logf((gw+1e-8f)/(aw+1e-8f)), t3 = logf((gh+1e-8f)/(ah+1e-8f));
        rs += sl1f(of0-t0) + sl1f(of1-t1) + sl1f(of2-t2) + sl1f(of3-t3);
      }

      const float pcx = acx + of0*aw, pcy = acy + of1*ah;
      const float pw = aw*expf(of2), ph = ah*expf(of3);
      float* op = out + 1 + (size_t)idx*4;
      op[0] = (pcx - pw*0.5f)*posf;
      op[1] = (pcy - ph*0.5f)*posf;
      op[2] = (pcx + pw*0.5f)*posf;
      op[3] = (pcy + ph*0.5f)*posf;
      out[1 + 4*(size_t)NB*NANC + idx] = posf;
    }
  }
#pragma unroll
  for (int o = 32; o > 0; o >>= 1) { cs += __shfl_xor(cs, o); rs += __shfl_xor(rs, o); }
  if ((t & 63) == 0) { atomicAdd(&sums[0], cs); atomicAdd(&sums[1], rs); }

  __syncthreads();
  if (t == 0) {
    __threadfence();
    const unsigned int c = atomicAdd(ctr, 1u);
    if (c == 63u) {                                   // 64 blocks total
      __threadfence();
      const float fcs = atomicAdd(&sums[0], 0.f);
      const float frs = atomicAdd(&sums[1], 0.f);
      out[0] = fcs*0.25f + 5.f*(frs*0.25f);           // w_conf*cls/B + w_reg*reg/B
    }
  }
}

extern "C" void kernel_launch(void* const* d_in, const int* in_sizes, int n_in,
                              void* d_out, int out_size, void* d_ws, size_t ws_size,
                              hipStream_t stream) {
  const float* x   = (const float*)d_in[0];
  const float* gtb = (const float*)d_in[1];
  // d_in[2] = gt_classes (unused by the loss)
  const float* w1  = (const float*)d_in[3];
  const float* b1  = (const float*)d_in[4];
  const float* cw  = (const float*)d_in[5];
  const float* cb  = (const float*)d_in[6];
  const float* rw  = (const float*)d_in[7];
  const float* rb  = (const float*)d_in[8];
  float* out = (float*)d_out;
  char* ws = (char*)d_ws;

  unsigned short* xh    = (unsigned short*)(ws + OFF_XH);
  unsigned short* wt    = (unsigned short*)(ws + OFF_WT);
  unsigned short* wh    = (unsigned short*)(ws + OFF_WH);
  float*          hb    = (float*)(ws + OFF_HB);
  unsigned int*   maxg  = (unsigned int*)(ws + OFF_MAXG);
  float*          sums  = (float*)(ws + OFF_SUMS);
  unsigned int*   ctr   = (unsigned int*)(ws + OFF_CTR);
  unsigned short* hidp  = (unsigned short*)(ws + OFF_HIDP);

  int nsplit = 8, ksh = 3;
  while (nsplit > 1 && OFF_HIDP + (size_t)nsplit*NM*NHID*2 > ws_size) { nsplit >>= 1; --ksh; }
  const int csplit = NC / nsplit;

  k_prep<<<PREP_NBLK, 256, 0, stream>>>(x, w1, cw, cb, rw, rb, gtb, xh, wt, wh, hb, maxg, sums, ctr);
  k_conv_gemm<<<128*nsplit, 256, 0, stream>>>(xh, wt, hidp, csplit, ksh);
  k_heads_assign<<<64, 256, 0, stream>>>(hidp, b1, wh, hb, gtb, maxg, out, sums, ctr, nsplit);
}

// Round 6
// 228.688 us; speedup vs baseline: 1.8216x; 1.0759x over previous
//
#include <hip/hip_runtime.h>

// RPN forward on gfx950. Heavy op = 3x3 conv (2048->512) = 77.3 GFLOP -> bf16 MFMA.
// R5: tail surgery. Heads GEMM = barrier-free register-fragment MFMA across 256 blocks
// (A-frag built in-registers from split-K partials; B-frag straight from global).
// w-transpose via LDS -> vectorized stores. Conv unchanged (1067 TF, L2-resident).

typedef __bf16 bf16x8 __attribute__((ext_vector_type(8)));
typedef float floatx4 __attribute__((ext_vector_type(4)));

#define NB 4
#define NC 2048
#define NH 32
#define NW 32
#define NHID 512
#define NA 9
#define NG 20
#define NANC 9216
#define NM 4096

// workspace layout (bytes)
#define OFF_XH    0ull            // [4][34][34][2048] bf16 (zero halo) = 18939904
#define OFF_WT    18939904ull     // [9][512][2048]    bf16 = 18874368
#define OFF_WH    37814272ull     // [48][512]         bf16 =    49152
#define OFF_HB    37863424ull     // [48]              f32  (pad 256)
#define OFF_MAXG  37863680ull     // [4][20] uint bits (pad 512)
#define OFF_SUMS  37864192ull     // [2] f32 (pad 128)
#define OFF_CTR   37864320ull     // [1] uint (pad 128)
#define OFF_HIDP  37864448ull     // [nsplit][4096][512] bf16, 4194304 each

// k_prep block ranges
#define PREP_TX   4096
#define PREP_W    1024            // 512 o * 2 halves, LDS-staged
#define PREP_WH   96
#define PREP_HALO 528
#define PREP_MAXG 80
#define PREP_NBLK (PREP_TX + PREP_W + PREP_WH + PREP_HALO + PREP_MAXG + 1)

__device__ __forceinline__ unsigned short f2bf(float f) {
  unsigned int u = __float_as_uint(f);
  u = (u + 0x7fffu + ((u >> 16) & 1u)) >> 16;   // RNE
  return (unsigned short)u;
}

__device__ __forceinline__ void gload16(const void* g, void* l) {
  __builtin_amdgcn_global_load_lds(
      (const __attribute__((address_space(1))) unsigned int*)g,
      (__attribute__((address_space(3))) unsigned int*)l, 16, 0, 0);
}

__constant__ float c_aw[9] = {2.f,2.f,2.f,4.f,4.f,4.f,6.f,6.f,6.f};
__constant__ float c_ah[9] = {1.f,2.f,3.f,2.f,4.f,6.f,3.f,6.f,9.f};

// ---- shared strict-f32 anchor/IoU helpers (bit-identical in prep-maxg + assign) ----
struct Anc { float x1, y1, x2, y2, areaA; };
__device__ __forceinline__ Anc anc_of(int n) {
  const int a = n % 9, pix = n / 9;
  const int xi = pix & 31, yi = pix >> 5;
  const float hw = c_aw[a]*0.5f, hh = c_ah[a]*0.5f;
  const float xc = xi + 0.5f, yc = yi + 0.5f;
  Anc A;
  A.x1 = fminf(fmaxf(xc - hw, 0.f), 32.f);
  A.y1 = fminf(fmaxf(yc - hh, 0.f), 32.f);
  A.x2 = fminf(fmaxf(xc + hw, 0.f), 32.f);
  A.y2 = fminf(fmaxf(yc + hh, 0.f), 32.f);
  A.areaA = __fmul_rn(__fsub_rn(A.x2, A.x1), __fsub_rn(A.y2, A.y1));
  return A;
}
__device__ __forceinline__ float iou_one(const Anc& A, float4 gp) {
  const float gx1 = gp.x * 0.03125f, gy1 = gp.y * 0.03125f;   // /32 exact
  const float gx2 = gp.z * 0.03125f, gy2 = gp.w * 0.03125f;
  const float dx = fmaxf(__fsub_rn(fminf(A.x2, gx2), fmaxf(A.x1, gx1)), 0.f);
  const float dy = fmaxf(__fsub_rn(fminf(A.y2, gy2), fmaxf(A.y1, gy1)), 0.f);
  const float inter = __fmul_rn(dx, dy);
  const float areaG = __fmul_rn(__fsub_rn(gx2, gx1), __fsub_rn(gy2, gy1));
  const float den = __fadd_rn(__fsub_rn(__fadd_rn(A.areaA, areaG), inter), 1e-8f);
  return __fdiv_rn(inter, den);
}

// ---------------- fused prep ----------------
__global__ __launch_bounds__(256) void k_prep(const float* __restrict__ x,
                                              const float* __restrict__ w1,
                                              const float* __restrict__ cw, const float* __restrict__ cb,
                                              const float* __restrict__ rw, const float* __restrict__ rb,
                                              const float* __restrict__ gtb,
                                              unsigned short* __restrict__ xh,
                                              unsigned short* __restrict__ wt,
                                              unsigned short* __restrict__ wh, float* __restrict__ hb,
                                              unsigned int* __restrict__ maxg,
                                              float* __restrict__ sums, unsigned int* __restrict__ ctr) {
  __shared__ float tile[64][33];
  __shared__ unsigned short wlds[9*1024];
  __shared__ float red[4];
  const int bid = blockIdx.x;
  const int tid = threadIdx.x;

  if (bid < PREP_TX) {                       // ---- x: NCHW f32 -> halo NHWC bf16
    const int c0 = (bid & 31) << 6;
    const int h  = (bid >> 5) & 31;
    const int b  = bid >> 10;
    const int w = tid & 31, cl = tid >> 5;
    const float* src = x + (((size_t)b*NC + c0)*NH + h)*NW;
#pragma unroll
    for (int j = 0; j < 8; ++j) {
      const int c = cl + j*8;
      tile[c][w] = src[(size_t)c*NH*NW + w];
    }
    __syncthreads();
    unsigned short* dst = xh + ((size_t)(b*34 + h + 1)*34 + 1)*2048 + c0;
    const int w2 = tid >> 3, c8 = (tid & 7) << 3;   // 16B store per lane
    unsigned int pk[4];
#pragma unroll
    for (int k = 0; k < 4; ++k) {
      const unsigned int lo = f2bf(tile[c8 + 2*k][w2]);
      const unsigned int hi = f2bf(tile[c8 + 2*k + 1][w2]);
      pk[k] = lo | (hi << 16);
    }
    *(uint4*)(dst + (size_t)w2*2048 + c8) = make_uint4(pk[0], pk[1], pk[2], pk[3]);
    return;
  }
  if (bid < PREP_TX + PREP_W) {              // ---- w1 -> [g][O][C] bf16, LDS-staged
    const int p = bid - PREP_TX;
    const int o = p >> 1, half = p & 1;
    const int c_base = half << 10;
    const float* src = w1 + ((size_t)(o*2048 + c_base))*9;   // 9216 contiguous floats
#pragma unroll
    for (int j = 0; j < 9; ++j) {            // read float4, scatter bf16 into [g][c] LDS
      const int f0 = (j*256 + tid)*4;
      const float4 v = *(const float4*)(src + f0);
      const float vv[4] = {v.x, v.y, v.z, v.w};
#pragma unroll
      for (int e = 0; e < 4; ++e) {
        const int f = f0 + e;
        const int c = f/9, g = f - c*9;
        wlds[g*1024 + c] = f2bf(vv[e]);
      }
    }
    __syncthreads();
#pragma unroll
    for (int j = 0; j < 5; ++j) {            // 1152 uint4 writes (9 g * 128)
      const int idx = j*256 + tid;
      if (idx < 1152) {
        const int g = idx >> 7, off = (idx & 127) << 3;
        *(uint4*)(wt + (size_t)g*NHID*NC + o*2048 + c_base + off) =
            *(const uint4*)(wlds + g*1024 + off);
      }
    }
    return;
  }
  if (bid < PREP_TX + PREP_W + PREP_WH) {    // ---- head weights [48][512] + bias
    const int t = (bid - PREP_TX - PREP_W)*256 + tid;
    const int n = t >> 9, c = t & 511;
    float v = 0.f;
    if (n < 9) v = cw[n*512 + c];
    else if (n < 45) v = rw[(n-9)*512 + c];
    wh[t] = f2bf(v);
    if (c == 0) {
      float bv = 0.f;
      if (n < 9) bv = cb[n];
      else if (n < 45) bv = rb[n-9];
      hb[n] = bv;
    }
    return;
  }
  if (bid < PREP_TX + PREP_W + PREP_WH + PREP_HALO) {  // ---- zero one halo cell
    const int q = bid - (PREP_TX + PREP_W + PREP_WH);
    const int b = q / 132, hc = q - b*132;
    int hh, ww;
    if (hc < 34)       { hh = 0;        ww = hc; }
    else if (hc < 68)  { hh = 33;       ww = hc - 34; }
    else if (hc < 100) { hh = hc - 67;  ww = 0; }
    else               { hh = hc - 99;  ww = 33; }
    uint4* dst = (uint4*)(xh + ((size_t)((b*34 + hh)*34 + ww))*2048);
    dst[tid] = make_uint4(0u, 0u, 0u, 0u);
    return;
  }
  if (bid < PREP_TX + PREP_W + PREP_WH + PREP_HALO + PREP_MAXG) {  // ---- maxg (b,g)
    const int p = bid - (PREP_TX + PREP_W + PREP_WH + PREP_HALO);
    const int b = p / NG, g = p - b*NG;
    const float4 gp = *(const float4*)(gtb + ((size_t)b*NG + g)*4);
    float m = 0.f;
#pragma unroll
    for (int j = 0; j < 36; ++j)
      m = fmaxf(m, iou_one(anc_of(tid + j*256), gp));
#pragma unroll
    for (int o = 32; o > 0; o >>= 1) m = fmaxf(m, __shfl_xor(m, o));
    if ((tid & 63) == 0) red[tid >> 6] = m;
    __syncthreads();
    if (tid == 0)
      maxg[b*NG + g] = __float_as_uint(fmaxf(fmaxf(red[0], red[1]), fmaxf(red[2], red[3])));
    return;
  }
  if (tid < 2) sums[tid] = 0.f;
  else if (tid == 2) *ctr = 0u;
}

// ---------------- conv 3x3 as implicit GEMM, bf16 MFMA, XCD-swizzled ----------------
__global__ __launch_bounds__(256, 4) void k_conv_gemm(const unsigned short* __restrict__ xh,
                                                      const unsigned short* __restrict__ wt,
                                                      unsigned short* __restrict__ hidp,
                                                      int csplit, int ksh) {
  __shared__ unsigned short As[128*64] __attribute__((aligned(16)));
  __shared__ unsigned short Bs[128*64] __attribute__((aligned(16)));
  const int t = threadIdx.x;
  const int L = blockIdx.x;
  const int kz = L & ((1 << ksh) - 1);
  const int rem = L >> ksh;
  const int tileM = rem & 31, tileN = rem >> 5;
  const int b = tileM >> 3, h0 = (tileM & 7) << 2;
  const int o0 = tileN << 7;
  const int wv = t >> 6, lane = t & 63;
  const int wm = wv >> 1, wn = wv & 1;
  const int quad = lane >> 4, l16 = lane & 15;
  const int c_base = kz * csplit;

  floatx4 acc[4][4];
#pragma unroll
  for (int mt = 0; mt < 4; ++mt)
#pragma unroll
    for (int nt = 0; nt < 4; ++nt)
      acc[mt][nt] = (floatx4){0.f, 0.f, 0.f, 0.f};

  const int lr = lane >> 3, pos = lane & 7;
  int gA[4], gB[4];
#pragma unroll
  for (int j = 0; j < 4; ++j) {
    const int row = wv*32 + j*8 + lr;
    const int sd = (pos - row) & 7;                   // seg swizzle (0 conflicts, measured)
    const int hh = h0 + (row >> 5) + 1, ww = (row & 31) + 1;
    gA[j] = ((b*34 + hh)*34 + ww)*2048 + c_base + sd*8;
    gB[j] = (o0 + row)*2048 + c_base + sd*8;
  }

  for (int g = 0; g < 9; ++g) {
    const int dsp = ((g/3 - 1)*34 + (g%3 - 1)) * 2048;
    const unsigned short* wgp = wt + (size_t)g*NHID*NC;
    for (int c0 = 0; c0 < csplit; c0 += 64) {
#pragma unroll
      for (int j = 0; j < 4; ++j) {
        gload16(xh + gA[j] + dsp + c0, As + (wv*32 + j*8)*64);
        gload16(wgp + gB[j] + c0,      Bs + (wv*32 + j*8)*64);
      }
      __syncthreads();
#pragma unroll
      for (int sub = 0; sub < 2; ++sub) {
        const int ps = ((sub*4 + quad) + l16) & 7;
        bf16x8 af[4], bw[4];
#pragma unroll
        for (int mt = 0; mt < 4; ++mt)
          af[mt] = *(const bf16x8*)(As + (wm*64 + mt*16 + l16)*64 + ps*8);
#pragma unroll
        for (int nt = 0; nt < 4; ++nt)
          bw[nt] = *(const bf16x8*)(Bs + (wn*64 + nt*16 + l16)*64 + ps*8);
#pragma unroll
        for (int mt = 0; mt < 4; ++mt)
#pragma unroll
          for (int nt = 0; nt < 4; ++nt)
            acc[mt][nt] = __builtin_amdgcn_mfma_f32_16x16x32_bf16(af[mt], bw[nt], acc[mt][nt], 0, 0, 0);
      }
      __syncthreads();
    }
  }
  unsigned short* hp = hidp + (size_t)kz*NM*NHID;
#pragma unroll
  for (int mt = 0; mt < 4; ++mt) {
    const int m = tileM*128 + wm*64 + mt*16 + quad*4;
#pragma unroll
    for (int nt = 0; nt < 4; ++nt) {
      const int o = o0 + wn*64 + nt*16 + l16;
#pragma unroll
      for (int r = 0; r < 4; ++r)
        hp[(size_t)(m + r)*NHID + o] = f2bf(acc[mt][nt][r]);
    }
  }
}

__device__ __forceinline__ float softplusf(float z) {
  return fmaxf(z, 0.f) + log1pf(expf(-fabsf(z)));
}
__device__ __forceinline__ float sl1f(float d) {
  const float ad = fabsf(d);
  return ad < 1.f ? 0.5f*d*d : ad - 0.5f;
}

// ---------------- heads GEMM (register fragments, no inner barriers) + assignment ----------------
// 256 blocks, 16 pixels each. Wave wv owns K-slice [wv*128, wv*128+128): builds A-frags
// in registers from split-K partials (+bias+ReLU), B-frags straight from wh. One barrier
// for the 4-wave cross-K reduce, then assignment for 144 anchors.
__global__ __launch_bounds__(256) void k_heads_assign(const unsigned short* __restrict__ hidp,
                                                      const float* __restrict__ b1,
                                                      const unsigned short* __restrict__ wh,
                                                      const float* __restrict__ hb,
                                                      const float* __restrict__ gtb,
                                                      const unsigned int* __restrict__ maxg,
                                                      float* __restrict__ out,
                                                      float* __restrict__ sums,
                                                      unsigned int* __restrict__ ctr,
                                                      int nsplit) {
  __shared__ float red[4][16][48];
  __shared__ float hl[16][49];
  __shared__ float4 gt_s[20];
  __shared__ float  mg_s[20];
  const int t = threadIdx.x;
  const int bid = blockIdx.x;
  const int b = bid >> 6, pix0 = (bid & 63) << 4;

  if (t < 20) {
    gt_s[t] = *(const float4*)(gtb + ((size_t)b*NG + t)*4);
    mg_s[t] = __uint_as_float(maxg[b*NG + t]);
  }

  const int wv = t >> 6, lane = t & 63;
  const int quad = lane >> 4, l16 = lane & 15;
  floatx4 acc[3];
#pragma unroll
  for (int nt = 0; nt < 3; ++nt) acc[nt] = (floatx4){0.f, 0.f, 0.f, 0.f};

  const int m = bid*16 + l16;                 // A row (global hid row)
#pragma unroll
  for (int kk = 0; kk < 4; ++kk) {
    const int ch0 = wv*128 + kk*32 + quad*8;  // this lane's 8 channels
    // A-frag: split-K reduce + bias + ReLU + pack, directly in A layout
    float s[8] = {0.f,0.f,0.f,0.f,0.f,0.f,0.f,0.f};
    const size_t gi = (size_t)m*NHID + ch0;
    for (int sp = 0; sp < nsplit; ++sp) {
      const uint4 v = *(const uint4*)(hidp + (size_t)sp*NM*NHID + gi);
      s[0] += __uint_as_float(v.x << 16); s[1] += __uint_as_float(v.x & 0xffff0000u);
      s[2] += __uint_as_float(v.y << 16); s[3] += __uint_as_float(v.y & 0xffff0000u);
      s[4] += __uint_as_float(v.z << 16); s[5] += __uint_as_float(v.z & 0xffff0000u);
      s[6] += __uint_as_float(v.w << 16); s[7] += __uint_as_float(v.w & 0xffff0000u);
    }
    union { unsigned short u[8]; bf16x8 v; } af;
#pragma unroll
    for (int e = 0; e < 8; ++e)
      af.u[e] = f2bf(fmaxf(s[e] + b1[ch0 + e], 0.f));
#pragma unroll
    for (int nt = 0; nt < 3; ++nt) {
      const bf16x8 bf = *(const bf16x8*)(wh + (size_t)(nt*16 + l16)*NHID + ch0);
      acc[nt] = __builtin_amdgcn_mfma_f32_16x16x32_bf16(af.v, bf, acc[nt], 0, 0, 0);
    }
  }
  // cross-wave K reduce: D row = quad*4+r, col = l16 (per m89 layout)
#pragma unroll
  for (int nt = 0; nt < 3; ++nt)
#pragma unroll
    for (int r = 0; r < 4; ++r)
      red[wv][quad*4 + r][nt*16 + l16] = acc[nt][r];
  __syncthreads();
#pragma unroll
  for (int j = 0; j < 3; ++j) {
    const int idx = t + j*256;                // 768 = 16*48 entries
    const int i = idx / 48, c = idx - i*48;
    hl[i][c] = red[0][i][c] + red[1][i][c] + red[2][i][c] + red[3][i][c] + hb[c];
  }
  __syncthreads();

  // ---- assignment, losses, proposals for this block's 144 anchors ----
  float cs = 0.f, rs = 0.f;
  if (t < 144) {
    const int pixL = t / 9, a = t - pixL*9;
    const int pix = pix0 + pixL;
    const int n = pix*9 + a;
    const int idx = b*NANC + n;
    const Anc A = anc_of(n);

    float mx = -1.f; int gi = 0; bool pos = false;
    for (int g = 0; g < NG; ++g) {
      const float v = iou_one(A, gt_s[g]);    // bit-identical to prep-maxg
      const float mg = mg_s[g];
      pos = pos || (v > 0.7f) || ((v == mg) && (mg > 1e-8f));
      if (v > mx) { mx = v; gi = g; }
    }
    const bool neg = (mx < 0.3f) && !pos;
    const float posf = pos ? 1.f : 0.f;

    const float conf = hl[pixL][a];
    const float of0 = hl[pixL][9 + a*4 + 0];
    const float of1 = hl[pixL][9 + a*4 + 1];
    const float of2 = hl[pixL][9 + a*4 + 2];
    const float of3 = hl[pixL][9 + a*4 + 3];

    if (pos) cs = softplusf(-conf);
    else if (neg) cs = softplusf(conf);

    const float acx = (A.x1 + A.x2)*0.5f, acy = (A.y1 + A.y2)*0.5f;
    const float aw = A.x2 - A.x1, ah = A.y2 - A.y1;
    if (pos) {
      const float4 gp = gt_s[gi];
      const float gx1 = gp.x*0.03125f, gy1 = gp.y*0.03125f;
      const float gx2 = gp.z*0.03125f, gy2 = gp.w*0.03125f;
      const float gcx = (gx1+gx2)*0.5f, gcy = (gy1+gy2)*0.5f;
      const float gw = gx2-gx1, gh = gy2-gy1;
      const float t0 = (gcx-acx)/(aw+1e-8f), t1 = (gcy-acy)/(ah+1e-8f);
      const float t2 = logf((gw+1e-8f)/(aw+1e-8f)), t3 = logf((gh+1e-8f)/(ah+1e-8f));
      rs = sl1f(of0-t0) + sl1f(of1-t1) + sl1f(of2-t2) + sl1f(of3-t3);
    }

    const float pcx = acx + of0*aw, pcy = acy + of1*ah;
    const float pw = aw*expf(of2), ph = ah*expf(of3);
    float* op = out + 1 + (size_t)idx*4;
    op[0] = (pcx - pw*0.5f)*posf;
    op[1] = (pcy - ph*0.5f)*posf;
    op[2] = (pcx + pw*0.5f)*posf;
    op[3] = (pcy + ph*0.5f)*posf;
    out[1 + 4*(size_t)NB*NANC + idx] = posf;
  }
#pragma unroll
  for (int o = 32; o > 0; o >>= 1) { cs += __shfl_xor(cs, o); rs += __shfl_xor(rs, o); }
  if ((t & 63) == 0) { atomicAdd(&sums[0], cs); atomicAdd(&sums[1], rs); }

  __syncthreads();
  if (t == 0) {
    __threadfence();
    const unsigned int c = atomicAdd(ctr, 1u);
    if (c == 255u) {                          // 256 blocks total
      __threadfence();
      const float fcs = atomicAdd(&sums[0], 0.f);
      const float frs = atomicAdd(&sums[1], 0.f);
      out[0] = fcs*0.25f + 5.f*(frs*0.25f);   // w_conf*cls/B + w_reg*reg/B
    }
  }
}

extern "C" void kernel_launch(void* const* d_in, const int* in_sizes, int n_in,
                              void* d_out, int out_size, void* d_ws, size_t ws_size,
                              hipStream_t stream) {
  const float* x   = (const float*)d_in[0];
  const float* gtb = (const float*)d_in[1];
  const float* w1  = (const float*)d_in[3];
  const float* b1  = (const float*)d_in[4];
  const float* cw  = (const float*)d_in[5];
  const float* cb  = (const float*)d_in[6];
  const float* rw  = (const float*)d_in[7];
  const float* rb  = (const float*)d_in[8];
  float* out = (float*)d_out;
  char* ws = (char*)d_ws;

  unsigned short* xh    = (unsigned short*)(ws + OFF_XH);
  unsigned short* wt    = (unsigned short*)(ws + OFF_WT);
  unsigned short* wh    = (unsigned short*)(ws + OFF_WH);
  float*          hb    = (float*)(ws + OFF_HB);
  unsigned int*   maxg  = (unsigned int*)(ws + OFF_MAXG);
  float*          sums  = (float*)(ws + OFF_SUMS);
  unsigned int*   ctr   = (unsigned int*)(ws + OFF_CTR);
  unsigned short* hidp  = (unsigned short*)(ws + OFF_HIDP);

  int nsplit = 8, ksh = 3;
  while (nsplit > 1 && OFF_HIDP + (size_t)nsplit*NM*NHID*2 > ws_size) { nsplit >>= 1; --ksh; }
  const int csplit = NC / nsplit;

  k_prep<<<PREP_NBLK, 256, 0, stream>>>(x, w1, cw, cb, rw, rb, gtb, xh, wt, wh, hb, maxg, sums, ctr);
  k_conv_gemm<<<128*nsplit, 256, 0, stream>>>(xh, wt, hidp, csplit, ksh);
  k_heads_assign<<<256, 256, 0, stream>>>(hidp, b1, wh, hb, gtb, maxg, out, sums, ctr, nsplit);
}